// Round 6
// baseline (251.234 us; speedup 1.0000x reference)
//
#include <hip/hip_runtime.h>

#define NPIX 49152   // B*H*W = 1*192*256
#define H_ 192
#define W_ 256
#define TPB 64       // tokens per chain block (64 tokens x 4 lanes = 256 thr)

// W-tile bank swizzle: col' = col + (col>>5)*4
#define WSWZ(c) ((c) + (((c) >> 5) << 2))

// ---------------------------------------------------------------------------
// both weight transposes (32 blocks) + zero binning counters (block 0)
// ---------------------------------------------------------------------------
__global__ __launch_bounds__(256) void wtrans2_k(const float* __restrict__ Wa,
    float* __restrict__ WTa, const float* __restrict__ Wb,
    float* __restrict__ WTb, int* __restrict__ S) {
  const int b = blockIdx.x;
  const float* __restrict__ W = (b < 16) ? Wa : Wb;
  float* __restrict__ WT = (b < 16) ? WTa : WTb;
  const int bb = b & 15;
  __shared__ float tile[32][33];
  const int bx = bb & 3, by = bb >> 2;
  const int c = threadIdx.x & 31, r0 = threadIdx.x >> 5;
#pragma unroll
  for (int j = 0; j < 4; ++j) {
    const int r = r0 + j * 8;
    tile[r][c] = W[(by * 32 + r) * 128 + bx * 32 + c];
  }
  __syncthreads();
#pragma unroll
  for (int j = 0; j < 4; ++j) {
    const int r = r0 + j * 8;
    WT[(bx * 32 + r) * 128 + by * 32 + c] = tile[c][r];
  }
  if (b == 0) {
    const int t = threadIdx.x;
    if (t < 32) S[t] = 0;        // cnt1 + cur1
    S[1088 + t] = 0;             // cnt2
    S[1344 + t] = 0;             // cur2
  }
}

// ---------------------------------------------------------------------------
// conv 128->128 as register-blocked GEMM (unchanged).
// ---------------------------------------------------------------------------
template<bool ACT>
__global__ __launch_bounds__(128) void conv128_v3(const float* __restrict__ X,
    const float* __restrict__ WT, const float* __restrict__ Bv,
    float* __restrict__ Y) {
  __shared__ float xb[2][16][32];
  __shared__ float wb[2][16][140];
  const int t = threadIdx.x;
  const int p0 = blockIdx.x * 32;
  const int to = t >> 3;
  const int tp = t & 7;
  const int wcol = WSWZ(to * 8);

  float acc[8][4];
#pragma unroll
  for (int i = 0; i < 8; ++i) {
    const float b = Bv[to * 8 + i];
#pragma unroll
    for (int j = 0; j < 4; ++j) acc[i][j] = b;
  }

  {
    const int k = t >> 3, c = (t & 7) * 4;
    *(float4*)(&xb[0][k][c]) = *(const float4*)(X + k * NPIX + p0 + c);
  }
#pragma unroll
  for (int j = 0; j < 4; ++j) {
    const int idx = t + j * 128, k = idx >> 5, c = (idx & 31) * 4;
    *(float4*)(&wb[0][k][WSWZ(c)]) = *(const float4*)(WT + k * 128 + c);
  }
  __syncthreads();

  for (int ch = 0; ch < 8; ++ch) {
    const int cur = ch & 1, nxt = cur ^ 1;
    float4 xs, ws[4];
    const int k1 = (ch + 1) * 16;
    if (ch < 7) {
      {
        const int k = t >> 3, c = (t & 7) * 4;
        xs = *(const float4*)(X + (k1 + k) * NPIX + p0 + c);
      }
#pragma unroll
      for (int j = 0; j < 4; ++j) {
        const int idx = t + j * 128, k = idx >> 5, c = (idx & 31) * 4;
        ws[j] = *(const float4*)(WT + (k1 + k) * 128 + c);
      }
    }
#pragma unroll
    for (int k = 0; k < 16; ++k) {
      float xv[4], wv[8];
      *(float4*)&xv[0] = *(const float4*)(&xb[cur][k][tp * 4]);
      *(float4*)&wv[0] = *(const float4*)(&wb[cur][k][wcol]);
      *(float4*)&wv[4] = *(const float4*)(&wb[cur][k][wcol + 4]);
#pragma unroll
      for (int i = 0; i < 8; ++i)
#pragma unroll
        for (int j = 0; j < 4; ++j)
          acc[i][j] = fmaf(wv[i], xv[j], acc[i][j]);
    }
    __syncthreads();
    if (ch < 7) {
      {
        const int k = t >> 3, c = (t & 7) * 4;
        *(float4*)(&xb[nxt][k][c]) = xs;
      }
#pragma unroll
      for (int j = 0; j < 4; ++j) {
        const int idx = t + j * 128, k = idx >> 5, c = (idx & 31) * 4;
        *(float4*)(&wb[nxt][k][WSWZ(c)]) = ws[j];
      }
      __syncthreads();
    }
  }

#pragma unroll
  for (int i = 0; i < 8; ++i) {
    float4 v;
    float* pv = (float*)&v;
#pragma unroll
    for (int j = 0; j < 4; ++j) {
      float x = acc[i][j];
      if (ACT) x = x > 0.f ? x : 0.01f * x;
      pv[j] = x;
    }
    *(float4*)(Y + (to * 8 + i) * NPIX + p0 + tp * 4) = v;
  }
}

// ---------------------------------------------------------------------------
// conv 128->17 + argmax + mask + fused inds1 histogram (unchanged).
// ---------------------------------------------------------------------------
__global__ __launch_bounds__(256) void conv17_k(const float* __restrict__ X,
    const float* __restrict__ W, const float* __restrict__ Bv,
    unsigned char* __restrict__ inds1, float* __restrict__ mask_out,
    int* __restrict__ cnt1) {
  __shared__ int lh[16];
  const int t = threadIdx.x;
  if (t < 16) lh[t] = 0;
  __syncthreads();
  const int p = blockIdx.x * 256 + t;
  float acc[17];
#pragma unroll
  for (int o = 0; o < 17; ++o) acc[o] = Bv[o];
  for (int k0 = 0; k0 < 128; k0 += 8) {
    float xv[8];
#pragma unroll
    for (int kk = 0; kk < 8; ++kk) xv[kk] = X[(k0 + kk) * NPIX + p];
#pragma unroll
    for (int o = 0; o < 17; ++o) {
#pragma unroll
      for (int kk = 0; kk < 8; ++kk)
        acc[o] = fmaf(xv[kk], W[o * 128 + k0 + kk], acc[o]);
    }
  }
  int am = 0;
  float bv = acc[0];
#pragma unroll
  for (int o = 1; o < 16; ++o) {
    if (acc[o] > bv) { bv = acc[o]; am = o; }
  }
  inds1[p] = (unsigned char)am;
  const float m = acc[16];
  mask_out[p] = m > 0.f ? m : 0.01f * m;
  atomicAdd(&lh[am], 1);
  __syncthreads();
  if (t < 16 && lh[t] > 0) atomicAdd(&cnt1[t], lh[t]);
}

// ---------------------------------------------------------------------------
// transpose x[k][h][w] -> xt[(w*H+h)*128 + k]
// ---------------------------------------------------------------------------
__global__ __launch_bounds__(256) void transpose_k(const float* __restrict__ X,
                                                   float* __restrict__ xt) {
  __shared__ float tile[32][33];
  const int w0 = (blockIdx.x & 7) * 32;
  const int k0 = ((blockIdx.x >> 3) & 3) * 32;
  const int h  = blockIdx.x >> 5;
  const int t = threadIdx.x;
  const int c = t & 31, rr = t >> 5;
#pragma unroll
  for (int j = 0; j < 4; ++j) {
    const int k = rr + j * 8;
    tile[k][c] = X[(k0 + k) * NPIX + h * W_ + w0 + c];
  }
  __syncthreads();
#pragma unroll
  for (int j = 0; j < 4; ++j) {
    const int w = rr + j * 8;
    xt[((w0 + w) * H_ + h) * 128 + k0 + c] = tile[c][w];
  }
}

// parallel scan + descriptor emit
template<int NB>
__global__ __launch_bounds__(256) void scan_desc_k(const int* __restrict__ cnt,
    int* __restrict__ off, int* __restrict__ desc, int* __restrict__ ndesc) {
  const int t = threadIdx.x;
  const int lane = t & 63, wvi = t >> 6;
  __shared__ int wsumC[4], wsumD[4];
  const int c = (t < NB) ? cnt[t] : 0;
  const int nb = (c + TPB - 1) / TPB;
  int ic = c, id = nb;
  for (int d = 1; d < 64; d <<= 1) {
    const int uc = __shfl_up(ic, d, 64);
    const int ud = __shfl_up(id, d, 64);
    if (lane >= d) { ic += uc; id += ud; }
  }
  if (lane == 63) { wsumC[wvi] = ic; wsumD[wvi] = id; }
  __syncthreads();
  int bc = 0, bd = 0;
#pragma unroll
  for (int w2 = 0; w2 < 4; ++w2) {
    if (w2 < wvi) { bc += wsumC[w2]; bd += wsumD[w2]; }
  }
  ic += bc; id += bd;
  if (t < NB) {
    off[t] = ic - c;
    const int db = id - nb;
    for (int j = 0; j < nb; ++j) desc[db + j] = (t << 12) | j;
  }
  if (t == NB - 1) *ndesc = id;
}

// two-level scatter
template<typename T>
__global__ __launch_bounds__(256) void scatter_k(const T* __restrict__ bins,
    const int* __restrict__ off, int* __restrict__ cursor,
    int* __restrict__ ord, int nbins) {
  __shared__ int lhist[256], lbase[256], lcur[256];
  const int t = threadIdx.x;
  const int n = blockIdx.x * 256 + t;
  if (t < nbins) { lhist[t] = 0; lcur[t] = 0; }
  __syncthreads();
  const int b = (int)bins[n];
  atomicAdd(&lhist[b], 1);
  __syncthreads();
  if (t < nbins && lhist[t] > 0) lbase[t] = atomicAdd(&cursor[t], lhist[t]);
  __syncthreads();
  const int r = atomicAdd(&lcur[b], 1);
  ord[off[b] + lbase[b] + r] = n;
}

// ---------------------------------------------------------------------------
// chain1 v3: 4 lanes per token, output-split (bitwise-identical chains).
// Each lane upfront-loads its QUARTER of the token row as 8 independent
// float4s (deep MLP); the k-ascending FMA loop shfl-broadcasts x from the
// owning lane. Values and accumulation order identical to v2.
// ---------------------------------------------------------------------------
__global__ __launch_bounds__(256) void chain1_k(const float* __restrict__ xt,
    const int* __restrict__ ord1, const int* __restrict__ off1,
    const int* __restrict__ cnt1, const int* __restrict__ desc1,
    const int* __restrict__ nd1,
    const float* __restrict__ wc21, const float* __restrict__ bc21,
    const float* __restrict__ wc22, const float* __restrict__ bc22,
    const float* __restrict__ wc23, const float* __restrict__ bc23,
    int* __restrict__ e12a, int* __restrict__ cnt2) {
  if ((int)blockIdx.x >= *nd1) return;
  __shared__ int lh[16];
  const int t = threadIdx.x;
  if (t < 16) lh[t] = 0;
  __syncthreads();
  const int tg = t >> 2, sub = t & 3;
  const int l0 = (t & 63) & ~3;          // group base lane within wave
  const int de = desc1[blockIdx.x];
  const int e = de >> 12, chunk = de & 0xFFF;
  const int cnt = cnt1[e];
  const int pos = chunk * TPB + tg;
  const bool valid = pos < cnt;
  const int n = valid ? ord1[off1[e] + pos] : 0;

  // upfront gather: lane owns k in [sub*32, sub*32+32) — 8 independent loads
  const float4* __restrict__ xq4 = (const float4*)(xt + n * 128 + sub * 32);
  float4 xq[8];
#pragma unroll
  for (int j = 0; j < 8; ++j) xq[j] = xq4[j];

  // L1: outputs sub*8..sub*8+7 over all 128 k (x via shfl from owner lane)
  const float* __restrict__ W1 = wc21 + e * 4096 + sub * 8;
  const float* __restrict__ B1 = bc21 + e * 32 + sub * 8;
  float a[8];
#pragma unroll
  for (int o = 0; o < 8; ++o) a[o] = B1[o];
#pragma unroll
  for (int k = 0; k < 128; ++k) {
    const float mine = ((const float*)&xq[(k & 31) >> 2])[k & 3];
    const float xv = __shfl(mine, l0 + (k >> 5), 64);
#pragma unroll
    for (int o = 0; o < 8; ++o)
      a[o] = fmaf(xv, W1[k * 32 + o], a[o]);
  }
#pragma unroll
  for (int o = 0; o < 8; ++o) a[o] = a[o] > 0.f ? a[o] : 0.01f * a[o];

  // L2: outputs sub*8..sub*8+7 over 32 inputs (shfl from group)
  const float* __restrict__ W2 = wc22 + e * 1024 + sub * 8;
  const float* __restrict__ B2 = bc22 + e * 32 + sub * 8;
  float b[8];
#pragma unroll
  for (int o = 0; o < 8; ++o) b[o] = B2[o];
#pragma unroll
  for (int i = 0; i < 32; ++i) {
    const float hv = __shfl(a[i & 7], l0 + (i >> 3), 64);
#pragma unroll
    for (int o = 0; o < 8; ++o)
      b[o] = fmaf(hv, W2[i * 32 + o], b[o]);
  }
#pragma unroll
  for (int o = 0; o < 8; ++o) b[o] = b[o] > 0.f ? b[o] : 0.01f * b[o];

  // L3: outputs sub*4..sub*4+3 (16 logits total)
  const float* __restrict__ W3 = wc23 + e * 512 + sub * 4;
  const float* __restrict__ B3 = bc23 + e * 16 + sub * 4;
  float s[4];
#pragma unroll
  for (int j = 0; j < 4; ++j) s[j] = B3[j];
#pragma unroll
  for (int i = 0; i < 32; ++i) {
    const float hv = __shfl(b[i & 7], l0 + (i >> 3), 64);
#pragma unroll
    for (int j = 0; j < 4; ++j)
      s[j] = fmaf(hv, W3[i * 16 + j], s[j]);
  }

  // argmax over 16: local first-max-wins, then min-index-of-max combine
  float bv = s[0];
  int bi = sub * 4;
#pragma unroll
  for (int j = 1; j < 4; ++j) {
    if (s[j] > bv) { bv = s[j]; bi = sub * 4 + j; }
  }
#pragma unroll
  for (int d = 1; d < 4; d <<= 1) {
    const float ov = __shfl_xor(bv, d, 64);
    const int oi = __shfl_xor(bi, d, 64);
    if (ov > bv || (ov == bv && oi < bi)) { bv = ov; bi = oi; }
  }
  const int e12 = e * 16 + bi;
  if (valid && sub == 0) {
    e12a[n] = e12;
    atomicAdd(&lh[bi], 1);
  }
  __syncthreads();
  if (t < 16 && lh[t] > 0)
    atomicAdd(&cnt2[e * 16 + t], lh[t]);
}

// ---------------------------------------------------------------------------
// chain2 v3: same upfront-gather structure. Writes out[n].
// ---------------------------------------------------------------------------
__global__ __launch_bounds__(256) void chain2_k(const float* __restrict__ xt,
    const int* __restrict__ ord2, const int* __restrict__ off2,
    const int* __restrict__ cnt2, const int* __restrict__ desc2,
    const int* __restrict__ nd2,
    const float* __restrict__ wr11, const float* __restrict__ br11,
    const float* __restrict__ wr12, const float* __restrict__ br12,
    const float* __restrict__ wr13, const float* __restrict__ br13,
    float* __restrict__ out) {
  if ((int)blockIdx.x >= *nd2) return;
  const int t = threadIdx.x;
  const int tg = t >> 2, sub = t & 3;
  const int l0 = (t & 63) & ~3;
  const int de = desc2[blockIdx.x];
  const int e12 = de >> 12, chunk = de & 0xFFF;
  const int cnt = cnt2[e12];
  const int pos = chunk * TPB + tg;
  const bool valid = pos < cnt;
  const int n = valid ? ord2[off2[e12] + pos] : 0;

  const float4* __restrict__ xq4 = (const float4*)(xt + n * 128 + sub * 32);
  float4 xq[8];
#pragma unroll
  for (int j = 0; j < 8; ++j) xq[j] = xq4[j];

  // L1: 128 -> 32, lane owns 8 outputs
  const float* __restrict__ W1 = wr11 + e12 * 4096 + sub * 8;
  const float* __restrict__ B1 = br11 + e12 * 32 + sub * 8;
  float a[8];
#pragma unroll
  for (int o = 0; o < 8; ++o) a[o] = B1[o];
#pragma unroll
  for (int k = 0; k < 128; ++k) {
    const float mine = ((const float*)&xq[(k & 31) >> 2])[k & 3];
    const float xv = __shfl(mine, l0 + (k >> 5), 64);
#pragma unroll
    for (int o = 0; o < 8; ++o)
      a[o] = fmaf(xv, W1[k * 32 + o], a[o]);
  }
#pragma unroll
  for (int o = 0; o < 8; ++o) a[o] = a[o] > 0.f ? a[o] : 0.01f * a[o];

  // L2: 32 -> 16, lane owns 4 outputs
  const float* __restrict__ W2 = wr12 + e12 * 512 + sub * 4;
  const float* __restrict__ B2 = br12 + e12 * 16 + sub * 4;
  float s[4];
#pragma unroll
  for (int j = 0; j < 4; ++j) s[j] = B2[j];
#pragma unroll
  for (int i = 0; i < 32; ++i) {
    const float hv = __shfl(a[i & 7], l0 + (i >> 3), 64);
#pragma unroll
    for (int j = 0; j < 4; ++j)
      s[j] = fmaf(hv, W2[i * 16 + j], s[j]);
  }
#pragma unroll
  for (int j = 0; j < 4; ++j) s[j] = s[j] > 0.f ? s[j] : 0.01f * s[j];

  // L3: 16 -> 1 (i ascending, bitwise same as before); lanes redundant
  float r = br13[e12];
  const float* __restrict__ W3 = wr13 + e12 * 16;
#pragma unroll
  for (int i = 0; i < 16; ++i) {
    const float hv = __shfl(s[i & 3], l0 + (i >> 2), 64);
    r = fmaf(hv, W3[i], r);
  }

  if (valid && sub == 0) out[n] = ((float)e12 + r) * (1.0f / 256.0f);
}

// ---------------------------------------------------------------------------
extern "C" void kernel_launch(void* const* d_in, const int* in_sizes, int n_in,
                              void* d_out, int out_size, void* d_ws,
                              size_t ws_size, hipStream_t stream) {
  const float* x_in  = (const float*)d_in[0];
  const float* w_c11 = (const float*)d_in[1];
  const float* b_c11 = (const float*)d_in[2];
  const float* w_c12 = (const float*)d_in[3];
  const float* b_c12 = (const float*)d_in[4];
  const float* w_c13 = (const float*)d_in[5];
  const float* b_c13 = (const float*)d_in[6];
  const float* w_c21 = (const float*)d_in[7];
  const float* b_c21 = (const float*)d_in[8];
  const float* w_c22 = (const float*)d_in[9];
  const float* b_c22 = (const float*)d_in[10];
  const float* w_c23 = (const float*)d_in[11];
  const float* b_c23 = (const float*)d_in[12];
  const float* w_r11 = (const float*)d_in[13];
  const float* b_r11 = (const float*)d_in[14];
  const float* w_r12 = (const float*)d_in[15];
  const float* b_r12 = (const float*)d_in[16];
  const float* w_r13 = (const float*)d_in[17];
  const float* b_r13 = (const float*)d_in[18];

  float* out = (float*)d_out;   // [0..N): x_real (token order), [N..2N): mask

  float* R0 = (float*)d_ws;
  float* R1 = R0 + 128 * NPIX;
  float* R2 = R1 + 128 * NPIX;

  float* y1 = R0;
  float* y2 = R1;
  float* xt = R0;
  unsigned char* inds1 = (unsigned char*)R2;   // N bytes
  float* wT1 = R2 + 12288;
  float* wT2 = wT1 + 16384;
  int* S = (int*)R2 + 45056;

  int* cnt1  = S;            // 16
  int* cur1  = S + 16;       // 16
  int* off1  = S + 32;       // 16
  int* nd1   = S + 48;       // 1 (+pad)
  int* desc1 = S + 64;       // 1024
  int* cnt2  = S + 1088;     // 256
  int* cur2  = S + 1344;     // 256
  int* off2  = S + 1600;     // 256
  int* nd2   = S + 1856;     // 1 (+pad)
  int* desc2 = S + 1872;     // 1024

  int* ib   = (int*)R1;
  int* ord1 = ib;            // N
  int* ord2 = ib + NPIX;     // N
  int* e12a = ib + 2 * NPIX; // N

  wtrans2_k<<<32, 256, 0, stream>>>(w_c11, wT1, w_c12, wT2, S);
  conv128_v3<true><<<NPIX / 32, 128, 0, stream>>>(x_in, wT1, b_c11, y1);
  conv128_v3<true><<<NPIX / 32, 128, 0, stream>>>(y1, wT2, b_c12, y2);
  transpose_k<<<192 * 32, 256, 0, stream>>>(x_in, xt);
  conv17_k<<<NPIX / 256, 256, 0, stream>>>(y2, w_c13, b_c13, inds1,
                                           out + NPIX, cnt1);
  scan_desc_k<16><<<1, 256, 0, stream>>>(cnt1, off1, desc1, nd1);
  scatter_k<unsigned char><<<NPIX / 256, 256, 0, stream>>>(inds1, off1, cur1,
                                                           ord1, 16);
  chain1_k<<<NPIX / TPB + 16, 256, 0, stream>>>(xt, ord1, off1, cnt1, desc1,
      nd1, w_c21, b_c21, w_c22, b_c22, w_c23, b_c23, e12a, cnt2);
  scan_desc_k<256><<<1, 256, 0, stream>>>(cnt2, off2, desc2, nd2);
  scatter_k<int><<<NPIX / 256, 256, 0, stream>>>(e12a, off2, cur2, ord2, 256);
  chain2_k<<<NPIX / TPB + 256, 256, 0, stream>>>(xt, ord2, off2, cnt2, desc2,
      nd2, w_r11, b_r11, w_r12, b_r12, w_r13, b_r13, out);
}

// Round 7
// 221.283 us; speedup vs baseline: 1.1354x; 1.1354x over previous
//
#include <hip/hip_runtime.h>

#define NPIX 49152   // B*H*W = 1*192*256
#define H_ 192
#define W_ 256
#define TPB 64       // tokens per chain block (64 tokens x 4 lanes = 256 thr)

// W-tile bank swizzle: col' = col + (col>>5)*4
#define WSWZ(c) ((c) + (((c) >> 5) << 2))

// ---------------------------------------------------------------------------
// both weight transposes (32 blocks) + zero binning counters (block 0)
// ---------------------------------------------------------------------------
__global__ __launch_bounds__(256) void wtrans2_k(const float* __restrict__ Wa,
    float* __restrict__ WTa, const float* __restrict__ Wb,
    float* __restrict__ WTb, int* __restrict__ S) {
  const int b = blockIdx.x;
  const float* __restrict__ W = (b < 16) ? Wa : Wb;
  float* __restrict__ WT = (b < 16) ? WTa : WTb;
  const int bb = b & 15;
  __shared__ float tile[32][33];
  const int bx = bb & 3, by = bb >> 2;
  const int c = threadIdx.x & 31, r0 = threadIdx.x >> 5;
#pragma unroll
  for (int j = 0; j < 4; ++j) {
    const int r = r0 + j * 8;
    tile[r][c] = W[(by * 32 + r) * 128 + bx * 32 + c];
  }
  __syncthreads();
#pragma unroll
  for (int j = 0; j < 4; ++j) {
    const int r = r0 + j * 8;
    WT[(bx * 32 + r) * 128 + by * 32 + c] = tile[c][r];
  }
  if (b == 0) {
    const int t = threadIdx.x;
    if (t < 32) S[t] = 0;        // cnt1 + cur1
    S[1088 + t] = 0;             // cnt2
    S[1344 + t] = 0;             // cur2
  }
}

// ---------------------------------------------------------------------------
// conv 128->128 as register-blocked GEMM (unchanged).
// ---------------------------------------------------------------------------
template<bool ACT>
__global__ __launch_bounds__(128) void conv128_v3(const float* __restrict__ X,
    const float* __restrict__ WT, const float* __restrict__ Bv,
    float* __restrict__ Y) {
  __shared__ float xb[2][16][32];
  __shared__ float wb[2][16][140];
  const int t = threadIdx.x;
  const int p0 = blockIdx.x * 32;
  const int to = t >> 3;
  const int tp = t & 7;
  const int wcol = WSWZ(to * 8);

  float acc[8][4];
#pragma unroll
  for (int i = 0; i < 8; ++i) {
    const float b = Bv[to * 8 + i];
#pragma unroll
    for (int j = 0; j < 4; ++j) acc[i][j] = b;
  }

  {
    const int k = t >> 3, c = (t & 7) * 4;
    *(float4*)(&xb[0][k][c]) = *(const float4*)(X + k * NPIX + p0 + c);
  }
#pragma unroll
  for (int j = 0; j < 4; ++j) {
    const int idx = t + j * 128, k = idx >> 5, c = (idx & 31) * 4;
    *(float4*)(&wb[0][k][WSWZ(c)]) = *(const float4*)(WT + k * 128 + c);
  }
  __syncthreads();

  for (int ch = 0; ch < 8; ++ch) {
    const int cur = ch & 1, nxt = cur ^ 1;
    float4 xs, ws[4];
    const int k1 = (ch + 1) * 16;
    if (ch < 7) {
      {
        const int k = t >> 3, c = (t & 7) * 4;
        xs = *(const float4*)(X + (k1 + k) * NPIX + p0 + c);
      }
#pragma unroll
      for (int j = 0; j < 4; ++j) {
        const int idx = t + j * 128, k = idx >> 5, c = (idx & 31) * 4;
        ws[j] = *(const float4*)(WT + (k1 + k) * 128 + c);
      }
    }
#pragma unroll
    for (int k = 0; k < 16; ++k) {
      float xv[4], wv[8];
      *(float4*)&xv[0] = *(const float4*)(&xb[cur][k][tp * 4]);
      *(float4*)&wv[0] = *(const float4*)(&wb[cur][k][wcol]);
      *(float4*)&wv[4] = *(const float4*)(&wb[cur][k][wcol + 4]);
#pragma unroll
      for (int i = 0; i < 8; ++i)
#pragma unroll
        for (int j = 0; j < 4; ++j)
          acc[i][j] = fmaf(wv[i], xv[j], acc[i][j]);
    }
    __syncthreads();
    if (ch < 7) {
      {
        const int k = t >> 3, c = (t & 7) * 4;
        *(float4*)(&xb[nxt][k][c]) = xs;
      }
#pragma unroll
      for (int j = 0; j < 4; ++j) {
        const int idx = t + j * 128, k = idx >> 5, c = (idx & 31) * 4;
        *(float4*)(&wb[nxt][k][WSWZ(c)]) = ws[j];
      }
      __syncthreads();
    }
  }

#pragma unroll
  for (int i = 0; i < 8; ++i) {
    float4 v;
    float* pv = (float*)&v;
#pragma unroll
    for (int j = 0; j < 4; ++j) {
      float x = acc[i][j];
      if (ACT) x = x > 0.f ? x : 0.01f * x;
      pv[j] = x;
    }
    *(float4*)(Y + (to * 8 + i) * NPIX + p0 + tp * 4) = v;
  }
}

// ---------------------------------------------------------------------------
// conv 128->17 + argmax + mask + fused inds1 histogram (unchanged).
// ---------------------------------------------------------------------------
__global__ __launch_bounds__(256) void conv17_k(const float* __restrict__ X,
    const float* __restrict__ W, const float* __restrict__ Bv,
    unsigned char* __restrict__ inds1, float* __restrict__ mask_out,
    int* __restrict__ cnt1) {
  __shared__ int lh[16];
  const int t = threadIdx.x;
  if (t < 16) lh[t] = 0;
  __syncthreads();
  const int p = blockIdx.x * 256 + t;
  float acc[17];
#pragma unroll
  for (int o = 0; o < 17; ++o) acc[o] = Bv[o];
  for (int k0 = 0; k0 < 128; k0 += 8) {
    float xv[8];
#pragma unroll
    for (int kk = 0; kk < 8; ++kk) xv[kk] = X[(k0 + kk) * NPIX + p];
#pragma unroll
    for (int o = 0; o < 17; ++o) {
#pragma unroll
      for (int kk = 0; kk < 8; ++kk)
        acc[o] = fmaf(xv[kk], W[o * 128 + k0 + kk], acc[o]);
    }
  }
  int am = 0;
  float bv = acc[0];
#pragma unroll
  for (int o = 1; o < 16; ++o) {
    if (acc[o] > bv) { bv = acc[o]; am = o; }
  }
  inds1[p] = (unsigned char)am;
  const float m = acc[16];
  mask_out[p] = m > 0.f ? m : 0.01f * m;
  atomicAdd(&lh[am], 1);
  __syncthreads();
  if (t < 16 && lh[t] > 0) atomicAdd(&cnt1[t], lh[t]);
}

// ---------------------------------------------------------------------------
// transpose x[k][h][w] -> xt[(w*H+h)*128 + k]
// ---------------------------------------------------------------------------
__global__ __launch_bounds__(256) void transpose_k(const float* __restrict__ X,
                                                   float* __restrict__ xt) {
  __shared__ float tile[32][33];
  const int w0 = (blockIdx.x & 7) * 32;
  const int k0 = ((blockIdx.x >> 3) & 3) * 32;
  const int h  = blockIdx.x >> 5;
  const int t = threadIdx.x;
  const int c = t & 31, rr = t >> 5;
#pragma unroll
  for (int j = 0; j < 4; ++j) {
    const int k = rr + j * 8;
    tile[k][c] = X[(k0 + k) * NPIX + h * W_ + w0 + c];
  }
  __syncthreads();
#pragma unroll
  for (int j = 0; j < 4; ++j) {
    const int w = rr + j * 8;
    xt[((w0 + w) * H_ + h) * 128 + k0 + c] = tile[c][w];
  }
}

// parallel scan + descriptor emit
template<int NB>
__global__ __launch_bounds__(256) void scan_desc_k(const int* __restrict__ cnt,
    int* __restrict__ off, int* __restrict__ desc, int* __restrict__ ndesc) {
  const int t = threadIdx.x;
  const int lane = t & 63, wvi = t >> 6;
  __shared__ int wsumC[4], wsumD[4];
  const int c = (t < NB) ? cnt[t] : 0;
  const int nb = (c + TPB - 1) / TPB;
  int ic = c, id = nb;
  for (int d = 1; d < 64; d <<= 1) {
    const int uc = __shfl_up(ic, d, 64);
    const int ud = __shfl_up(id, d, 64);
    if (lane >= d) { ic += uc; id += ud; }
  }
  if (lane == 63) { wsumC[wvi] = ic; wsumD[wvi] = id; }
  __syncthreads();
  int bc = 0, bd = 0;
#pragma unroll
  for (int w2 = 0; w2 < 4; ++w2) {
    if (w2 < wvi) { bc += wsumC[w2]; bd += wsumD[w2]; }
  }
  ic += bc; id += bd;
  if (t < NB) {
    off[t] = ic - c;
    const int db = id - nb;
    for (int j = 0; j < nb; ++j) desc[db + j] = (t << 12) | j;
  }
  if (t == NB - 1) *ndesc = id;
}

// two-level scatter
template<typename T>
__global__ __launch_bounds__(256) void scatter_k(const T* __restrict__ bins,
    const int* __restrict__ off, int* __restrict__ cursor,
    int* __restrict__ ord, int nbins) {
  __shared__ int lhist[256], lbase[256], lcur[256];
  const int t = threadIdx.x;
  const int n = blockIdx.x * 256 + t;
  if (t < nbins) { lhist[t] = 0; lcur[t] = 0; }
  __syncthreads();
  const int b = (int)bins[n];
  atomicAdd(&lhist[b], 1);
  __syncthreads();
  if (t < nbins && lhist[t] > 0) lbase[t] = atomicAdd(&cursor[t], lhist[t]);
  __syncthreads();
  const int r = atomicAdd(&lcur[b], 1);
  ord[off[b] + lbase[b] + r] = n;
}

// ---------------------------------------------------------------------------
// chain1 v4: 4 lanes per token, output-split. Token rows LDS-staged with 8
// independent float4 loads per lane (deep MLP on the scattered gather), then
// L1 reads x directly from LDS (ds_read_b128 broadcast, no shuffles).
// Accumulation per output: bias then k ascending — bitwise identical to v1-v3.
// ---------------------------------------------------------------------------
__global__ __launch_bounds__(256) void chain1_k(const float* __restrict__ xt,
    const int* __restrict__ ord1, const int* __restrict__ off1,
    const int* __restrict__ cnt1, const int* __restrict__ desc1,
    const int* __restrict__ nd1,
    const float* __restrict__ wc21, const float* __restrict__ bc21,
    const float* __restrict__ wc22, const float* __restrict__ bc22,
    const float* __restrict__ wc23, const float* __restrict__ bc23,
    int* __restrict__ e12a, int* __restrict__ cnt2) {
  if ((int)blockIdx.x >= *nd1) return;
  __shared__ float xs_[64][132];   // pad 132: even bank spread for r/w
  __shared__ int lh[16];
  const int t = threadIdx.x;
  if (t < 16) lh[t] = 0;
  const int tg = t >> 2, sub = t & 3;
  const int l0 = (t & 63) & ~3;          // group base lane within wave
  const int de = desc1[blockIdx.x];
  const int e = de >> 12, chunk = de & 0xFFF;
  const int cnt = cnt1[e];
  const int pos = chunk * TPB + tg;
  const bool valid = pos < cnt;
  const int n = valid ? ord1[off1[e] + pos] : 0;

  // stage: lane loads its quarter of the token row (8 independent float4s)
  {
    const float4* __restrict__ src = (const float4*)(xt + n * 128 + sub * 32);
    float4 tmp[8];
#pragma unroll
    for (int j = 0; j < 8; ++j) tmp[j] = src[j];
#pragma unroll
    for (int j = 0; j < 8; ++j)
      *(float4*)(&xs_[tg][sub * 32 + 4 * j]) = tmp[j];
  }
  __syncthreads();

  // L1: outputs sub*8..sub*8+7 over all 128 k (x from LDS, broadcast x4)
  const float* __restrict__ W1 = wc21 + e * 4096 + sub * 8;
  const float* __restrict__ B1 = bc21 + e * 32 + sub * 8;
  float a[8];
#pragma unroll
  for (int o = 0; o < 8; ++o) a[o] = B1[o];
#pragma unroll
  for (int k = 0; k < 128; k += 4) {
    float x4[4];
    *(float4*)x4 = *(const float4*)(&xs_[tg][k]);
#pragma unroll
    for (int kk = 0; kk < 4; ++kk)
#pragma unroll
      for (int o = 0; o < 8; ++o)
        a[o] = fmaf(x4[kk], W1[(k + kk) * 32 + o], a[o]);
  }
#pragma unroll
  for (int o = 0; o < 8; ++o) a[o] = a[o] > 0.f ? a[o] : 0.01f * a[o];

  // L2: outputs sub*8..sub*8+7 over 32 inputs (shfl from group)
  const float* __restrict__ W2 = wc22 + e * 1024 + sub * 8;
  const float* __restrict__ B2 = bc22 + e * 32 + sub * 8;
  float b[8];
#pragma unroll
  for (int o = 0; o < 8; ++o) b[o] = B2[o];
#pragma unroll
  for (int i = 0; i < 32; ++i) {
    const float hv = __shfl(a[i & 7], l0 + (i >> 3), 64);
#pragma unroll
    for (int o = 0; o < 8; ++o)
      b[o] = fmaf(hv, W2[i * 32 + o], b[o]);
  }
#pragma unroll
  for (int o = 0; o < 8; ++o) b[o] = b[o] > 0.f ? b[o] : 0.01f * b[o];

  // L3: outputs sub*4..sub*4+3 (16 logits total)
  const float* __restrict__ W3 = wc23 + e * 512 + sub * 4;
  const float* __restrict__ B3 = bc23 + e * 16 + sub * 4;
  float s[4];
#pragma unroll
  for (int j = 0; j < 4; ++j) s[j] = B3[j];
#pragma unroll
  for (int i = 0; i < 32; ++i) {
    const float hv = __shfl(b[i & 7], l0 + (i >> 3), 64);
#pragma unroll
    for (int j = 0; j < 4; ++j)
      s[j] = fmaf(hv, W3[i * 16 + j], s[j]);
  }

  // argmax over 16: local first-max-wins, then min-index-of-max combine
  float bv = s[0];
  int bi = sub * 4;
#pragma unroll
  for (int j = 1; j < 4; ++j) {
    if (s[j] > bv) { bv = s[j]; bi = sub * 4 + j; }
  }
#pragma unroll
  for (int d = 1; d < 4; d <<= 1) {
    const float ov = __shfl_xor(bv, d, 64);
    const int oi = __shfl_xor(bi, d, 64);
    if (ov > bv || (ov == bv && oi < bi)) { bv = ov; bi = oi; }
  }
  const int e12 = e * 16 + bi;
  if (valid && sub == 0) {
    e12a[n] = e12;
    atomicAdd(&lh[bi], 1);
  }
  __syncthreads();
  if (t < 16 && lh[t] > 0)
    atomicAdd(&cnt2[e * 16 + t], lh[t]);
}

// ---------------------------------------------------------------------------
// chain2 v4: same LDS-staged structure. Writes out[n].
// ---------------------------------------------------------------------------
__global__ __launch_bounds__(256) void chain2_k(const float* __restrict__ xt,
    const int* __restrict__ ord2, const int* __restrict__ off2,
    const int* __restrict__ cnt2, const int* __restrict__ desc2,
    const int* __restrict__ nd2,
    const float* __restrict__ wr11, const float* __restrict__ br11,
    const float* __restrict__ wr12, const float* __restrict__ br12,
    const float* __restrict__ wr13, const float* __restrict__ br13,
    float* __restrict__ out) {
  if ((int)blockIdx.x >= *nd2) return;
  __shared__ float xs_[64][132];
  const int t = threadIdx.x;
  const int tg = t >> 2, sub = t & 3;
  const int l0 = (t & 63) & ~3;
  const int de = desc2[blockIdx.x];
  const int e12 = de >> 12, chunk = de & 0xFFF;
  const int cnt = cnt2[e12];
  const int pos = chunk * TPB + tg;
  const bool valid = pos < cnt;
  const int n = valid ? ord2[off2[e12] + pos] : 0;

  {
    const float4* __restrict__ src = (const float4*)(xt + n * 128 + sub * 32);
    float4 tmp[8];
#pragma unroll
    for (int j = 0; j < 8; ++j) tmp[j] = src[j];
#pragma unroll
    for (int j = 0; j < 8; ++j)
      *(float4*)(&xs_[tg][sub * 32 + 4 * j]) = tmp[j];
  }
  __syncthreads();

  // L1: 128 -> 32, lane owns 8 outputs
  const float* __restrict__ W1 = wr11 + e12 * 4096 + sub * 8;
  const float* __restrict__ B1 = br11 + e12 * 32 + sub * 8;
  float a[8];
#pragma unroll
  for (int o = 0; o < 8; ++o) a[o] = B1[o];
#pragma unroll
  for (int k = 0; k < 128; k += 4) {
    float x4[4];
    *(float4*)x4 = *(const float4*)(&xs_[tg][k]);
#pragma unroll
    for (int kk = 0; kk < 4; ++kk)
#pragma unroll
      for (int o = 0; o < 8; ++o)
        a[o] = fmaf(x4[kk], W1[(k + kk) * 32 + o], a[o]);
  }
#pragma unroll
  for (int o = 0; o < 8; ++o) a[o] = a[o] > 0.f ? a[o] : 0.01f * a[o];

  // L2: 32 -> 16, lane owns 4 outputs
  const float* __restrict__ W2 = wr12 + e12 * 512 + sub * 4;
  const float* __restrict__ B2 = br12 + e12 * 16 + sub * 4;
  float s[4];
#pragma unroll
  for (int j = 0; j < 4; ++j) s[j] = B2[j];
#pragma unroll
  for (int i = 0; i < 32; ++i) {
    const float hv = __shfl(a[i & 7], l0 + (i >> 3), 64);
#pragma unroll
    for (int j = 0; j < 4; ++j)
      s[j] = fmaf(hv, W2[i * 16 + j], s[j]);
  }
#pragma unroll
  for (int j = 0; j < 4; ++j) s[j] = s[j] > 0.f ? s[j] : 0.01f * s[j];

  // L3: 16 -> 1 (i ascending, bitwise same as before); lanes redundant
  float r = br13[e12];
  const float* __restrict__ W3 = wr13 + e12 * 16;
#pragma unroll
  for (int i = 0; i < 16; ++i) {
    const float hv = __shfl(s[i & 3], l0 + (i >> 2), 64);
    r = fmaf(hv, W3[i], r);
  }

  if (valid && sub == 0) out[n] = ((float)e12 + r) * (1.0f / 256.0f);
}

// ---------------------------------------------------------------------------
extern "C" void kernel_launch(void* const* d_in, const int* in_sizes, int n_in,
                              void* d_out, int out_size, void* d_ws,
                              size_t ws_size, hipStream_t stream) {
  const float* x_in  = (const float*)d_in[0];
  const float* w_c11 = (const float*)d_in[1];
  const float* b_c11 = (const float*)d_in[2];
  const float* w_c12 = (const float*)d_in[3];
  const float* b_c12 = (const float*)d_in[4];
  const float* w_c13 = (const float*)d_in[5];
  const float* b_c13 = (const float*)d_in[6];
  const float* w_c21 = (const float*)d_in[7];
  const float* b_c21 = (const float*)d_in[8];
  const float* w_c22 = (const float*)d_in[9];
  const float* b_c22 = (const float*)d_in[10];
  const float* w_c23 = (const float*)d_in[11];
  const float* b_c23 = (const float*)d_in[12];
  const float* w_r11 = (const float*)d_in[13];
  const float* b_r11 = (const float*)d_in[14];
  const float* w_r12 = (const float*)d_in[15];
  const float* b_r12 = (const float*)d_in[16];
  const float* w_r13 = (const float*)d_in[17];
  const float* b_r13 = (const float*)d_in[18];

  float* out = (float*)d_out;   // [0..N): x_real (token order), [N..2N): mask

  float* R0 = (float*)d_ws;
  float* R1 = R0 + 128 * NPIX;
  float* R2 = R1 + 128 * NPIX;

  float* y1 = R0;
  float* y2 = R1;
  float* xt = R0;
  unsigned char* inds1 = (unsigned char*)R2;   // N bytes
  float* wT1 = R2 + 12288;
  float* wT2 = wT1 + 16384;
  int* S = (int*)R2 + 45056;

  int* cnt1  = S;            // 16
  int* cur1  = S + 16;       // 16
  int* off1  = S + 32;       // 16
  int* nd1   = S + 48;       // 1 (+pad)
  int* desc1 = S + 64;       // 1024
  int* cnt2  = S + 1088;     // 256
  int* cur2  = S + 1344;     // 256
  int* off2  = S + 1600;     // 256
  int* nd2   = S + 1856;     // 1 (+pad)
  int* desc2 = S + 1872;     // 1024

  int* ib   = (int*)R1;
  int* ord1 = ib;            // N
  int* ord2 = ib + NPIX;     // N
  int* e12a = ib + 2 * NPIX; // N

  wtrans2_k<<<32, 256, 0, stream>>>(w_c11, wT1, w_c12, wT2, S);
  conv128_v3<true><<<NPIX / 32, 128, 0, stream>>>(x_in, wT1, b_c11, y1);
  conv128_v3<true><<<NPIX / 32, 128, 0, stream>>>(y1, wT2, b_c12, y2);
  transpose_k<<<192 * 32, 256, 0, stream>>>(x_in, xt);
  conv17_k<<<NPIX / 256, 256, 0, stream>>>(y2, w_c13, b_c13, inds1,
                                           out + NPIX, cnt1);
  scan_desc_k<16><<<1, 256, 0, stream>>>(cnt1, off1, desc1, nd1);
  scatter_k<unsigned char><<<NPIX / 256, 256, 0, stream>>>(inds1, off1, cur1,
                                                           ord1, 16);
  chain1_k<<<NPIX / TPB + 16, 256, 0, stream>>>(xt, ord1, off1, cnt1, desc1,
      nd1, w_c21, b_c21, w_c22, b_c22, w_c23, b_c23, e12a, cnt2);
  scan_desc_k<256><<<1, 256, 0, stream>>>(cnt2, off2, desc2, nd2);
  scatter_k<int><<<NPIX / 256, 256, 0, stream>>>(e12a, off2, cur2, ord2, 256);
  chain2_k<<<NPIX / TPB + 256, 256, 0, stream>>>(xt, ord2, off2, cnt2, desc2,
      nd2, w_r11, b_r11, w_r12, b_r12, w_r13, b_r13, out);
}

// Round 8
// 180.802 us; speedup vs baseline: 1.3896x; 1.2239x over previous
//
#include <hip/hip_runtime.h>

#define NPIX 49152   // B*H*W = 1*192*256
#define H_ 192
#define W_ 256
#define TPB 64       // tokens per chain block (64 tokens x 4 lanes = 256 thr)

// W-tile bank swizzle: col' = col + (col>>5)*4
#define WSWZ(c) ((c) + (((c) >> 5) << 2))

// ---------------------------------------------------------------------------
// both weight transposes (32 blocks) + zero binning counters (block 0)
// ---------------------------------------------------------------------------
__global__ __launch_bounds__(256) void wtrans2_k(const float* __restrict__ Wa,
    float* __restrict__ WTa, const float* __restrict__ Wb,
    float* __restrict__ WTb, int* __restrict__ S) {
  const int b = blockIdx.x;
  const float* __restrict__ W = (b < 16) ? Wa : Wb;
  float* __restrict__ WT = (b < 16) ? WTa : WTb;
  const int bb = b & 15;
  __shared__ float tile[32][33];
  const int bx = bb & 3, by = bb >> 2;
  const int c = threadIdx.x & 31, r0 = threadIdx.x >> 5;
#pragma unroll
  for (int j = 0; j < 4; ++j) {
    const int r = r0 + j * 8;
    tile[r][c] = W[(by * 32 + r) * 128 + bx * 32 + c];
  }
  __syncthreads();
#pragma unroll
  for (int j = 0; j < 4; ++j) {
    const int r = r0 + j * 8;
    WT[(bx * 32 + r) * 128 + by * 32 + c] = tile[c][r];
  }
  if (b == 0) {
    const int t = threadIdx.x;
    if (t < 32) S[t] = 0;        // cnt1 + cur1
    S[1088 + t] = 0;             // cnt2
    S[1344 + t] = 0;             // cur2
  }
}

// ---------------------------------------------------------------------------
// conv 128->128 as register-blocked GEMM (unchanged).
// ---------------------------------------------------------------------------
template<bool ACT>
__global__ __launch_bounds__(128) void conv128_v3(const float* __restrict__ X,
    const float* __restrict__ WT, const float* __restrict__ Bv,
    float* __restrict__ Y) {
  __shared__ float xb[2][16][32];
  __shared__ float wb[2][16][140];
  const int t = threadIdx.x;
  const int p0 = blockIdx.x * 32;
  const int to = t >> 3;
  const int tp = t & 7;
  const int wcol = WSWZ(to * 8);

  float acc[8][4];
#pragma unroll
  for (int i = 0; i < 8; ++i) {
    const float b = Bv[to * 8 + i];
#pragma unroll
    for (int j = 0; j < 4; ++j) acc[i][j] = b;
  }

  {
    const int k = t >> 3, c = (t & 7) * 4;
    *(float4*)(&xb[0][k][c]) = *(const float4*)(X + k * NPIX + p0 + c);
  }
#pragma unroll
  for (int j = 0; j < 4; ++j) {
    const int idx = t + j * 128, k = idx >> 5, c = (idx & 31) * 4;
    *(float4*)(&wb[0][k][WSWZ(c)]) = *(const float4*)(WT + k * 128 + c);
  }
  __syncthreads();

  for (int ch = 0; ch < 8; ++ch) {
    const int cur = ch & 1, nxt = cur ^ 1;
    float4 xs, ws[4];
    const int k1 = (ch + 1) * 16;
    if (ch < 7) {
      {
        const int k = t >> 3, c = (t & 7) * 4;
        xs = *(const float4*)(X + (k1 + k) * NPIX + p0 + c);
      }
#pragma unroll
      for (int j = 0; j < 4; ++j) {
        const int idx = t + j * 128, k = idx >> 5, c = (idx & 31) * 4;
        ws[j] = *(const float4*)(WT + (k1 + k) * 128 + c);
      }
    }
#pragma unroll
    for (int k = 0; k < 16; ++k) {
      float xv[4], wv[8];
      *(float4*)&xv[0] = *(const float4*)(&xb[cur][k][tp * 4]);
      *(float4*)&wv[0] = *(const float4*)(&wb[cur][k][wcol]);
      *(float4*)&wv[4] = *(const float4*)(&wb[cur][k][wcol + 4]);
#pragma unroll
      for (int i = 0; i < 8; ++i)
#pragma unroll
        for (int j = 0; j < 4; ++j)
          acc[i][j] = fmaf(wv[i], xv[j], acc[i][j]);
    }
    __syncthreads();
    if (ch < 7) {
      {
        const int k = t >> 3, c = (t & 7) * 4;
        *(float4*)(&xb[nxt][k][c]) = xs;
      }
#pragma unroll
      for (int j = 0; j < 4; ++j) {
        const int idx = t + j * 128, k = idx >> 5, c = (idx & 31) * 4;
        *(float4*)(&wb[nxt][k][WSWZ(c)]) = ws[j];
      }
      __syncthreads();
    }
  }

#pragma unroll
  for (int i = 0; i < 8; ++i) {
    float4 v;
    float* pv = (float*)&v;
#pragma unroll
    for (int j = 0; j < 4; ++j) {
      float x = acc[i][j];
      if (ACT) x = x > 0.f ? x : 0.01f * x;
      pv[j] = x;
    }
    *(float4*)(Y + (to * 8 + i) * NPIX + p0 + tp * 4) = v;
  }
}

// ---------------------------------------------------------------------------
// conv 128->17 + argmax + mask + fused inds1 histogram (unchanged).
// ---------------------------------------------------------------------------
__global__ __launch_bounds__(256) void conv17_k(const float* __restrict__ X,
    const float* __restrict__ W, const float* __restrict__ Bv,
    unsigned char* __restrict__ inds1, float* __restrict__ mask_out,
    int* __restrict__ cnt1) {
  __shared__ int lh[16];
  const int t = threadIdx.x;
  if (t < 16) lh[t] = 0;
  __syncthreads();
  const int p = blockIdx.x * 256 + t;
  float acc[17];
#pragma unroll
  for (int o = 0; o < 17; ++o) acc[o] = Bv[o];
  for (int k0 = 0; k0 < 128; k0 += 8) {
    float xv[8];
#pragma unroll
    for (int kk = 0; kk < 8; ++kk) xv[kk] = X[(k0 + kk) * NPIX + p];
#pragma unroll
    for (int o = 0; o < 17; ++o) {
#pragma unroll
      for (int kk = 0; kk < 8; ++kk)
        acc[o] = fmaf(xv[kk], W[o * 128 + k0 + kk], acc[o]);
    }
  }
  int am = 0;
  float bv = acc[0];
#pragma unroll
  for (int o = 1; o < 16; ++o) {
    if (acc[o] > bv) { bv = acc[o]; am = o; }
  }
  inds1[p] = (unsigned char)am;
  const float m = acc[16];
  mask_out[p] = m > 0.f ? m : 0.01f * m;
  atomicAdd(&lh[am], 1);
  __syncthreads();
  if (t < 16 && lh[t] > 0) atomicAdd(&cnt1[t], lh[t]);
}

// ---------------------------------------------------------------------------
// transpose x[k][h][w] -> xt[(w*H+h)*128 + k]
// ---------------------------------------------------------------------------
__global__ __launch_bounds__(256) void transpose_k(const float* __restrict__ X,
                                                   float* __restrict__ xt) {
  __shared__ float tile[32][33];
  const int w0 = (blockIdx.x & 7) * 32;
  const int k0 = ((blockIdx.x >> 3) & 3) * 32;
  const int h  = blockIdx.x >> 5;
  const int t = threadIdx.x;
  const int c = t & 31, rr = t >> 5;
#pragma unroll
  for (int j = 0; j < 4; ++j) {
    const int k = rr + j * 8;
    tile[k][c] = X[(k0 + k) * NPIX + h * W_ + w0 + c];
  }
  __syncthreads();
#pragma unroll
  for (int j = 0; j < 4; ++j) {
    const int w = rr + j * 8;
    xt[((w0 + w) * H_ + h) * 128 + k0 + c] = tile[c][w];
  }
}

// parallel scan + descriptor emit
template<int NB>
__global__ __launch_bounds__(256) void scan_desc_k(const int* __restrict__ cnt,
    int* __restrict__ off, int* __restrict__ desc, int* __restrict__ ndesc) {
  const int t = threadIdx.x;
  const int lane = t & 63, wvi = t >> 6;
  __shared__ int wsumC[4], wsumD[4];
  const int c = (t < NB) ? cnt[t] : 0;
  const int nb = (c + TPB - 1) / TPB;
  int ic = c, id = nb;
  for (int d = 1; d < 64; d <<= 1) {
    const int uc = __shfl_up(ic, d, 64);
    const int ud = __shfl_up(id, d, 64);
    if (lane >= d) { ic += uc; id += ud; }
  }
  if (lane == 63) { wsumC[wvi] = ic; wsumD[wvi] = id; }
  __syncthreads();
  int bc = 0, bd = 0;
#pragma unroll
  for (int w2 = 0; w2 < 4; ++w2) {
    if (w2 < wvi) { bc += wsumC[w2]; bd += wsumD[w2]; }
  }
  ic += bc; id += bd;
  if (t < NB) {
    off[t] = ic - c;
    const int db = id - nb;
    for (int j = 0; j < nb; ++j) desc[db + j] = (t << 12) | j;
  }
  if (t == NB - 1) *ndesc = id;
}

// two-level scatter
template<typename T>
__global__ __launch_bounds__(256) void scatter_k(const T* __restrict__ bins,
    const int* __restrict__ off, int* __restrict__ cursor,
    int* __restrict__ ord, int nbins) {
  __shared__ int lhist[256], lbase[256], lcur[256];
  const int t = threadIdx.x;
  const int n = blockIdx.x * 256 + t;
  if (t < nbins) { lhist[t] = 0; lcur[t] = 0; }
  __syncthreads();
  const int b = (int)bins[n];
  atomicAdd(&lhist[b], 1);
  __syncthreads();
  if (t < nbins && lhist[t] > 0) lbase[t] = atomicAdd(&cursor[t], lhist[t]);
  __syncthreads();
  const int r = atomicAdd(&lcur[b], 1);
  ord[off[b] + lbase[b] + r] = n;
}

// ---------------------------------------------------------------------------
// chain1 v5: 4 lanes per token, output-split; expert WEIGHTS staged in LDS
// cooperatively (coalesced, ~23KB), x rows staged as before. Hot loop is
// pure LDS (broadcast ds_read_b128) — no VMEM in the k-loop.
// Per-output accumulation: bias then k ascending — bitwise identical.
// ---------------------------------------------------------------------------
__global__ __launch_bounds__(256) void chain1_k(const float* __restrict__ xt,
    const int* __restrict__ ord1, const int* __restrict__ off1,
    const int* __restrict__ cnt1, const int* __restrict__ desc1,
    const int* __restrict__ nd1,
    const float* __restrict__ wc21, const float* __restrict__ bc21,
    const float* __restrict__ wc22, const float* __restrict__ bc22,
    const float* __restrict__ wc23, const float* __restrict__ bc23,
    int* __restrict__ e12a, int* __restrict__ cnt2) {
  if ((int)blockIdx.x >= *nd1) return;
  __shared__ float w1s[4096];      // 16 KB  [k][o] k-major (same as global)
  __shared__ float w2s[1024];      // 4 KB
  __shared__ float w3s[512];       // 2 KB
  __shared__ float bs[80];         // b1[32] b2[32] b3[16]
  __shared__ float xs_[64][132];   // 33.8 KB
  __shared__ int lh[16];
  const int t = threadIdx.x;
  if (t < 16) lh[t] = 0;
  const int tg = t >> 2, sub = t & 3;
  const int l0 = (t & 63) & ~3;          // group base lane within wave
  const int de = desc1[blockIdx.x];
  const int e = de >> 12, chunk = de & 0xFFF;
  const int cnt = cnt1[e];
  const int pos = chunk * TPB + tg;
  const bool valid = pos < cnt;
  const int n = valid ? ord1[off1[e] + pos] : 0;

  // ---- stage expert weights (coalesced, fully independent loads) ----
  {
    const float4* __restrict__ Wg1 = (const float4*)(wc21 + e * 4096);
#pragma unroll
    for (int j = 0; j < 4; ++j)
      *(float4*)&w1s[t * 4 + j * 1024] = Wg1[t + j * 256];
    const float4* __restrict__ Wg2 = (const float4*)(wc22 + e * 1024);
    *(float4*)&w2s[t * 4] = Wg2[t];
    if (t < 128) {
      const float4* __restrict__ Wg3 = (const float4*)(wc23 + e * 512);
      *(float4*)&w3s[t * 4] = Wg3[t];
    }
    if (t < 32) bs[t] = bc21[e * 32 + t];
    else if (t < 64) bs[t] = bc22[e * 32 + (t - 32)];
    else if (t < 80) bs[t] = bc23[e * 16 + (t - 64)];
  }

  // ---- stage token rows (8 independent float4 per lane) ----
  {
    const float4* __restrict__ src = (const float4*)(xt + n * 128 + sub * 32);
    float4 tmp[8];
#pragma unroll
    for (int j = 0; j < 8; ++j) tmp[j] = src[j];
#pragma unroll
    for (int j = 0; j < 8; ++j)
      *(float4*)(&xs_[tg][sub * 32 + 4 * j]) = tmp[j];
  }
  __syncthreads();

  const int wb1 = sub * 8;

  // L1: outputs sub*8..sub*8+7 over all 128 k (x + w from LDS)
  float a[8];
#pragma unroll
  for (int o = 0; o < 8; ++o) a[o] = bs[wb1 + o];
#pragma unroll
  for (int k = 0; k < 128; k += 4) {
    float x4[4];
    *(float4*)x4 = *(const float4*)(&xs_[tg][k]);
#pragma unroll
    for (int kk = 0; kk < 4; ++kk) {
      float w8[8];
      *(float4*)&w8[0] = *(const float4*)&w1s[(k + kk) * 32 + wb1];
      *(float4*)&w8[4] = *(const float4*)&w1s[(k + kk) * 32 + wb1 + 4];
#pragma unroll
      for (int o = 0; o < 8; ++o) a[o] = fmaf(x4[kk], w8[o], a[o]);
    }
  }
#pragma unroll
  for (int o = 0; o < 8; ++o) a[o] = a[o] > 0.f ? a[o] : 0.01f * a[o];

  // L2: outputs sub*8..sub*8+7 over 32 inputs (shfl from group, w from LDS)
  float b[8];
#pragma unroll
  for (int o = 0; o < 8; ++o) b[o] = bs[32 + wb1 + o];
#pragma unroll
  for (int i = 0; i < 32; ++i) {
    const float hv = __shfl(a[i & 7], l0 + (i >> 3), 64);
    float w8[8];
    *(float4*)&w8[0] = *(const float4*)&w2s[i * 32 + wb1];
    *(float4*)&w8[4] = *(const float4*)&w2s[i * 32 + wb1 + 4];
#pragma unroll
    for (int o = 0; o < 8; ++o) b[o] = fmaf(hv, w8[o], b[o]);
  }
#pragma unroll
  for (int o = 0; o < 8; ++o) b[o] = b[o] > 0.f ? b[o] : 0.01f * b[o];

  // L3: outputs sub*4..sub*4+3 (16 logits total)
  float s[4];
#pragma unroll
  for (int j = 0; j < 4; ++j) s[j] = bs[64 + sub * 4 + j];
#pragma unroll
  for (int i = 0; i < 32; ++i) {
    const float hv = __shfl(b[i & 7], l0 + (i >> 3), 64);
    float w4[4];
    *(float4*)w4 = *(const float4*)&w3s[i * 16 + sub * 4];
#pragma unroll
    for (int j = 0; j < 4; ++j) s[j] = fmaf(hv, w4[j], s[j]);
  }

  // argmax over 16: local first-max-wins, then min-index-of-max combine
  float bv = s[0];
  int bi = sub * 4;
#pragma unroll
  for (int j = 1; j < 4; ++j) {
    if (s[j] > bv) { bv = s[j]; bi = sub * 4 + j; }
  }
#pragma unroll
  for (int d = 1; d < 4; d <<= 1) {
    const float ov = __shfl_xor(bv, d, 64);
    const int oi = __shfl_xor(bi, d, 64);
    if (ov > bv || (ov == bv && oi < bi)) { bv = ov; bi = oi; }
  }
  const int e12 = e * 16 + bi;
  if (valid && sub == 0) {
    e12a[n] = e12;
    atomicAdd(&lh[bi], 1);
  }
  __syncthreads();
  if (t < 16 && lh[t] > 0)
    atomicAdd(&cnt2[e * 16 + t], lh[t]);
}

// ---------------------------------------------------------------------------
// chain2 v5: same LDS-weight-staged structure. Writes out[n].
// ---------------------------------------------------------------------------
__global__ __launch_bounds__(256) void chain2_k(const float* __restrict__ xt,
    const int* __restrict__ ord2, const int* __restrict__ off2,
    const int* __restrict__ cnt2, const int* __restrict__ desc2,
    const int* __restrict__ nd2,
    const float* __restrict__ wr11, const float* __restrict__ br11,
    const float* __restrict__ wr12, const float* __restrict__ br12,
    const float* __restrict__ wr13, const float* __restrict__ br13,
    float* __restrict__ out) {
  if ((int)blockIdx.x >= *nd2) return;
  __shared__ float w1s[4096];      // 16 KB
  __shared__ float w2s[512];       // 2 KB
  __shared__ float w3s[16];
  __shared__ float bs[49];         // b1[32] b2[16] b3[1]
  __shared__ float xs_[64][132];
  const int t = threadIdx.x;
  const int tg = t >> 2, sub = t & 3;
  const int l0 = (t & 63) & ~3;
  const int de = desc2[blockIdx.x];
  const int e12 = de >> 12, chunk = de & 0xFFF;
  const int cnt = cnt2[e12];
  const int pos = chunk * TPB + tg;
  const bool valid = pos < cnt;
  const int n = valid ? ord2[off2[e12] + pos] : 0;

  // ---- stage expert weights ----
  {
    const float4* __restrict__ Wg1 = (const float4*)(wr11 + e12 * 4096);
#pragma unroll
    for (int j = 0; j < 4; ++j)
      *(float4*)&w1s[t * 4 + j * 1024] = Wg1[t + j * 256];
    if (t < 128) {
      const float4* __restrict__ Wg2 = (const float4*)(wr12 + e12 * 512);
      *(float4*)&w2s[t * 4] = Wg2[t];
    }
    if (t < 16) w3s[t] = wr13[e12 * 16 + t];
    if (t < 32) bs[t] = br11[e12 * 32 + t];
    else if (t < 48) bs[t] = br12[e12 * 16 + (t - 32)];
    else if (t == 48) bs[48] = br13[e12];
  }

  // ---- stage token rows ----
  {
    const float4* __restrict__ src = (const float4*)(xt + n * 128 + sub * 32);
    float4 tmp[8];
#pragma unroll
    for (int j = 0; j < 8; ++j) tmp[j] = src[j];
#pragma unroll
    for (int j = 0; j < 8; ++j)
      *(float4*)(&xs_[tg][sub * 32 + 4 * j]) = tmp[j];
  }
  __syncthreads();

  const int wb1 = sub * 8;

  // L1: 128 -> 32, lane owns 8 outputs
  float a[8];
#pragma unroll
  for (int o = 0; o < 8; ++o) a[o] = bs[wb1 + o];
#pragma unroll
  for (int k = 0; k < 128; k += 4) {
    float x4[4];
    *(float4*)x4 = *(const float4*)(&xs_[tg][k]);
#pragma unroll
    for (int kk = 0; kk < 4; ++kk) {
      float w8[8];
      *(float4*)&w8[0] = *(const float4*)&w1s[(k + kk) * 32 + wb1];
      *(float4*)&w8[4] = *(const float4*)&w1s[(k + kk) * 32 + wb1 + 4];
#pragma unroll
      for (int o = 0; o < 8; ++o) a[o] = fmaf(x4[kk], w8[o], a[o]);
    }
  }
#pragma unroll
  for (int o = 0; o < 8; ++o) a[o] = a[o] > 0.f ? a[o] : 0.01f * a[o];

  // L2: 32 -> 16, lane owns 4 outputs
  float s[4];
#pragma unroll
  for (int j = 0; j < 4; ++j) s[j] = bs[32 + sub * 4 + j];
#pragma unroll
  for (int i = 0; i < 32; ++i) {
    const float hv = __shfl(a[i & 7], l0 + (i >> 3), 64);
    float w4[4];
    *(float4*)w4 = *(const float4*)&w2s[i * 16 + sub * 4];
#pragma unroll
    for (int j = 0; j < 4; ++j) s[j] = fmaf(hv, w4[j], s[j]);
  }
#pragma unroll
  for (int j = 0; j < 4; ++j) s[j] = s[j] > 0.f ? s[j] : 0.01f * s[j];

  // L3: 16 -> 1 (i ascending, bitwise same as before); lanes redundant
  float r = bs[48];
#pragma unroll
  for (int i = 0; i < 16; ++i) {
    const float hv = __shfl(s[i & 3], l0 + (i >> 2), 64);
    r = fmaf(hv, w3s[i], r);
  }

  if (valid && sub == 0) out[n] = ((float)e12 + r) * (1.0f / 256.0f);
}

// ---------------------------------------------------------------------------
extern "C" void kernel_launch(void* const* d_in, const int* in_sizes, int n_in,
                              void* d_out, int out_size, void* d_ws,
                              size_t ws_size, hipStream_t stream) {
  const float* x_in  = (const float*)d_in[0];
  const float* w_c11 = (const float*)d_in[1];
  const float* b_c11 = (const float*)d_in[2];
  const float* w_c12 = (const float*)d_in[3];
  const float* b_c12 = (const float*)d_in[4];
  const float* w_c13 = (const float*)d_in[5];
  const float* b_c13 = (const float*)d_in[6];
  const float* w_c21 = (const float*)d_in[7];
  const float* b_c21 = (const float*)d_in[8];
  const float* w_c22 = (const float*)d_in[9];
  const float* b_c22 = (const float*)d_in[10];
  const float* w_c23 = (const float*)d_in[11];
  const float* b_c23 = (const float*)d_in[12];
  const float* w_r11 = (const float*)d_in[13];
  const float* b_r11 = (const float*)d_in[14];
  const float* w_r12 = (const float*)d_in[15];
  const float* b_r12 = (const float*)d_in[16];
  const float* w_r13 = (const float*)d_in[17];
  const float* b_r13 = (const float*)d_in[18];

  float* out = (float*)d_out;   // [0..N): x_real (token order), [N..2N): mask

  float* R0 = (float*)d_ws;
  float* R1 = R0 + 128 * NPIX;
  float* R2 = R1 + 128 * NPIX;

  float* y1 = R0;
  float* y2 = R1;
  float* xt = R0;
  unsigned char* inds1 = (unsigned char*)R2;   // N bytes
  float* wT1 = R2 + 12288;
  float* wT2 = wT1 + 16384;
  int* S = (int*)R2 + 45056;

  int* cnt1  = S;            // 16
  int* cur1  = S + 16;       // 16
  int* off1  = S + 32;       // 16
  int* nd1   = S + 48;       // 1 (+pad)
  int* desc1 = S + 64;       // 1024
  int* cnt2  = S + 1088;     // 256
  int* cur2  = S + 1344;     // 256
  int* off2  = S + 1600;     // 256
  int* nd2   = S + 1856;     // 1 (+pad)
  int* desc2 = S + 1872;     // 1024

  int* ib   = (int*)R1;
  int* ord1 = ib;            // N
  int* ord2 = ib + NPIX;     // N
  int* e12a = ib + 2 * NPIX; // N

  wtrans2_k<<<32, 256, 0, stream>>>(w_c11, wT1, w_c12, wT2, S);
  conv128_v3<true><<<NPIX / 32, 128, 0, stream>>>(x_in, wT1, b_c11, y1);
  conv128_v3<true><<<NPIX / 32, 128, 0, stream>>>(y1, wT2, b_c12, y2);
  transpose_k<<<192 * 32, 256, 0, stream>>>(x_in, xt);
  conv17_k<<<NPIX / 256, 256, 0, stream>>>(y2, w_c13, b_c13, inds1,
                                           out + NPIX, cnt1);
  scan_desc_k<16><<<1, 256, 0, stream>>>(cnt1, off1, desc1, nd1);
  scatter_k<unsigned char><<<NPIX / 256, 256, 0, stream>>>(inds1, off1, cur1,
                                                           ord1, 16);
  chain1_k<<<NPIX / TPB + 16, 256, 0, stream>>>(xt, ord1, off1, cnt1, desc1,
      nd1, w_c21, b_c21, w_c22, b_c22, w_c23, b_c23, e12a, cnt2);
  scan_desc_k<256><<<1, 256, 0, stream>>>(cnt2, off2, desc2, nd2);
  scatter_k<int><<<NPIX / 256, 256, 0, stream>>>(e12a, off2, cur2, ord2, 256);
  chain2_k<<<NPIX / TPB + 256, 256, 0, stream>>>(xt, ord2, off2, cnt2, desc2,
      nd2, w_r11, b_r11, w_r12, b_r12, w_r13, b_r13, out);
}

// Round 9
// 172.329 us; speedup vs baseline: 1.4579x; 1.0492x over previous
//
#include <hip/hip_runtime.h>

#define NPIX 49152   // B*H*W = 1*192*256
#define H_ 192
#define W_ 256
#define TPB 64       // tokens per chain block (64 tokens x 4 lanes = 256 thr)

// W-tile bank swizzle: col' = col + (col>>5)*4
#define WSWZ(c) ((c) + (((c) >> 5) << 2))

// ---------------------------------------------------------------------------
// both weight transposes (32 blocks) + zero binning counters (block 0)
// ---------------------------------------------------------------------------
__global__ __launch_bounds__(256) void wtrans2_k(const float* __restrict__ Wa,
    float* __restrict__ WTa, const float* __restrict__ Wb,
    float* __restrict__ WTb, int* __restrict__ S) {
  const int b = blockIdx.x;
  const float* __restrict__ W = (b < 16) ? Wa : Wb;
  float* __restrict__ WT = (b < 16) ? WTa : WTb;
  const int bb = b & 15;
  __shared__ float tile[32][33];
  const int bx = bb & 3, by = bb >> 2;
  const int c = threadIdx.x & 31, r0 = threadIdx.x >> 5;
#pragma unroll
  for (int j = 0; j < 4; ++j) {
    const int r = r0 + j * 8;
    tile[r][c] = W[(by * 32 + r) * 128 + bx * 32 + c];
  }
  __syncthreads();
#pragma unroll
  for (int j = 0; j < 4; ++j) {
    const int r = r0 + j * 8;
    WT[(bx * 32 + r) * 128 + by * 32 + c] = tile[c][r];
  }
  if (b == 0) {
    const int t = threadIdx.x;
    if (t < 32) S[t] = 0;        // cnt1 + cur1
    S[1088 + t] = 0;             // cnt2
    S[1344 + t] = 0;             // cur2
  }
}

// ---------------------------------------------------------------------------
// FUSED conv1 + conv2 + conv17 + argmax + mask + histogram.
// Block: 128 threads, 32 pixels, all 128 channels. Intermediates live in LDS
// (xs2), never touch global. Per-output FMA chains (bias then k ascending)
// are bitwise identical to the previous separate kernels.
// ---------------------------------------------------------------------------
__global__ __launch_bounds__(128) void convfused_k(const float* __restrict__ X,
    const float* __restrict__ WT1, const float* __restrict__ Bv1,
    const float* __restrict__ WT2, const float* __restrict__ Bv2,
    const float* __restrict__ W3, const float* __restrict__ Bv3,
    unsigned char* __restrict__ inds1, float* __restrict__ mask_out,
    int* __restrict__ cnt1) {
  __shared__ float xb[2][16][32];     // 4 KB   phase-1 X staging
  __shared__ float wpool[2][16][140]; // 17.9 KB W staging; then W3 [k][20]
  __shared__ float xs2[128][34];      // 17 KB  inter-phase activations
  __shared__ int lh[16];
  const int t = threadIdx.x;
  const int p0 = blockIdx.x * 32;
  const int to = t >> 3;              // 0..15: outputs to*8..to*8+7
  const int tp = t & 7;               // 0..7 : pixels  tp*4..tp*4+3
  const int wcol = WSWZ(to * 8);
  if (t < 16) lh[t] = 0;

  float acc[8][4];

  // ================= PHASE 1: conv1 (X global, W1 LDS) =================
#pragma unroll
  for (int i = 0; i < 8; ++i) {
    const float b = Bv1[to * 8 + i];
#pragma unroll
    for (int j = 0; j < 4; ++j) acc[i][j] = b;
  }
  {
    const int k = t >> 3, c = (t & 7) * 4;
    *(float4*)(&xb[0][k][c]) = *(const float4*)(X + k * NPIX + p0 + c);
  }
#pragma unroll
  for (int j = 0; j < 4; ++j) {
    const int idx = t + j * 128, k = idx >> 5, c = (idx & 31) * 4;
    *(float4*)(&wpool[0][k][WSWZ(c)]) = *(const float4*)(WT1 + k * 128 + c);
  }
  __syncthreads();

  for (int ch = 0; ch < 8; ++ch) {
    const int cur = ch & 1, nxt = cur ^ 1;
    float4 xs, ws[4];
    const int k1 = (ch + 1) * 16;
    if (ch < 7) {
      {
        const int k = t >> 3, c = (t & 7) * 4;
        xs = *(const float4*)(X + (k1 + k) * NPIX + p0 + c);
      }
#pragma unroll
      for (int j = 0; j < 4; ++j) {
        const int idx = t + j * 128, k = idx >> 5, c = (idx & 31) * 4;
        ws[j] = *(const float4*)(WT1 + (k1 + k) * 128 + c);
      }
    }
#pragma unroll
    for (int k = 0; k < 16; ++k) {
      float xv[4], wv[8];
      *(float4*)&xv[0] = *(const float4*)(&xb[cur][k][tp * 4]);
      *(float4*)&wv[0] = *(const float4*)(&wpool[cur][k][wcol]);
      *(float4*)&wv[4] = *(const float4*)(&wpool[cur][k][wcol + 4]);
#pragma unroll
      for (int i = 0; i < 8; ++i)
#pragma unroll
        for (int j = 0; j < 4; ++j)
          acc[i][j] = fmaf(wv[i], xv[j], acc[i][j]);
    }
    __syncthreads();
    if (ch < 7) {
      {
        const int k = t >> 3, c = (t & 7) * 4;
        *(float4*)(&xb[nxt][k][c]) = xs;
      }
#pragma unroll
      for (int j = 0; j < 4; ++j) {
        const int idx = t + j * 128, k = idx >> 5, c = (idx & 31) * 4;
        *(float4*)(&wpool[nxt][k][WSWZ(c)]) = ws[j];
      }
      __syncthreads();
    }
  }

  // epilogue 1: lrelu -> xs2 ; prologue 2: stage W2 chunk 0 (wpool free)
#pragma unroll
  for (int i = 0; i < 8; ++i) {
    float v[4];
#pragma unroll
    for (int j = 0; j < 4; ++j) {
      const float x = acc[i][j];
      v[j] = x > 0.f ? x : 0.01f * x;
    }
    *(float2*)(&xs2[to * 8 + i][tp * 4])     = *(float2*)&v[0];
    *(float2*)(&xs2[to * 8 + i][tp * 4 + 2]) = *(float2*)&v[2];
  }
#pragma unroll
  for (int j = 0; j < 4; ++j) {
    const int idx = t + j * 128, k = idx >> 5, c = (idx & 31) * 4;
    *(float4*)(&wpool[0][k][WSWZ(c)]) = *(const float4*)(WT2 + k * 128 + c);
  }
  __syncthreads();

  // ================= PHASE 2: conv2 (x from xs2, W2 LDS) =================
#pragma unroll
  for (int i = 0; i < 8; ++i) {
    const float b = Bv2[to * 8 + i];
#pragma unroll
    for (int j = 0; j < 4; ++j) acc[i][j] = b;
  }
  for (int ch = 0; ch < 8; ++ch) {
    const int cur = ch & 1, nxt = cur ^ 1;
    float4 ws[4];
    const int k1 = (ch + 1) * 16;
    if (ch < 7) {
#pragma unroll
      for (int j = 0; j < 4; ++j) {
        const int idx = t + j * 128, k = idx >> 5, c = (idx & 31) * 4;
        ws[j] = *(const float4*)(WT2 + (k1 + k) * 128 + c);
      }
    }
    const int k0 = ch * 16;
#pragma unroll
    for (int k = 0; k < 16; ++k) {
      float xv[4], wv[8];
      *(float2*)&xv[0] = *(const float2*)(&xs2[k0 + k][tp * 4]);
      *(float2*)&xv[2] = *(const float2*)(&xs2[k0 + k][tp * 4 + 2]);
      *(float4*)&wv[0] = *(const float4*)(&wpool[cur][k][wcol]);
      *(float4*)&wv[4] = *(const float4*)(&wpool[cur][k][wcol + 4]);
#pragma unroll
      for (int i = 0; i < 8; ++i)
#pragma unroll
        for (int j = 0; j < 4; ++j)
          acc[i][j] = fmaf(wv[i], xv[j], acc[i][j]);
    }
    __syncthreads();
    if (ch < 7) {
#pragma unroll
      for (int j = 0; j < 4; ++j) {
        const int idx = t + j * 128, k = idx >> 5, c = (idx & 31) * 4;
        *(float4*)(&wpool[nxt][k][WSWZ(c)]) = ws[j];
      }
      __syncthreads();
    }
  }

  // epilogue 2: lrelu -> xs2 (all reads done: post-ch7 barrier passed);
  // stage W3 into freed wpool as w3s[k][20] (o-minor, float4-readable)
  float* w3s = &wpool[0][0][0];
#pragma unroll
  for (int i = 0; i < 8; ++i) {
    float v[4];
#pragma unroll
    for (int j = 0; j < 4; ++j) {
      const float x = acc[i][j];
      v[j] = x > 0.f ? x : 0.01f * x;
    }
    *(float2*)(&xs2[to * 8 + i][tp * 4])     = *(float2*)&v[0];
    *(float2*)(&xs2[to * 8 + i][tp * 4 + 2]) = *(float2*)&v[2];
  }
  for (int i = t; i < 17 * 128; i += 128)
    w3s[(i & 127) * 20 + (i >> 7)] = W3[i];
  __syncthreads();

  // ================= PHASE 3: conv17 + argmax + mask + hist =============
  {
    const int p = t >> 2, sub = t & 3;       // 4 lanes per pixel
    const int l0 = (t & 63) & ~3;
    float s4[4];
#pragma unroll
    for (int j = 0; j < 4; ++j) s4[j] = Bv3[sub * 4 + j];
    float m = Bv3[16];
#pragma unroll 8
    for (int k = 0; k < 128; ++k) {
      const float xv = xs2[k][p];
      float w4[4];
      *(float4*)w4 = *(const float4*)&w3s[k * 20 + sub * 4];
#pragma unroll
      for (int j = 0; j < 4; ++j) s4[j] = fmaf(xv, w4[j], s4[j]);
      m = fmaf(xv, w3s[k * 20 + 16], m);
    }
    // argmax over 16: per-lane first-max-wins, then min-index-of-max combine
    float bv = s4[0];
    int bi = sub * 4;
#pragma unroll
    for (int j = 1; j < 4; ++j) {
      if (s4[j] > bv) { bv = s4[j]; bi = sub * 4 + j; }
    }
#pragma unroll
    for (int d = 1; d < 4; d <<= 1) {
      const float ov = __shfl_xor(bv, d, 64);
      const int oi = __shfl_xor(bi, d, 64);
      if (ov > bv || (ov == bv && oi < bi)) { bv = ov; bi = oi; }
    }
    if (sub == 0) {
      inds1[p0 + p] = (unsigned char)bi;
      mask_out[p0 + p] = m > 0.f ? m : 0.01f * m;
      atomicAdd(&lh[bi], 1);
    }
  }
  __syncthreads();
  if (t < 16 && lh[t] > 0) atomicAdd(&cnt1[t], lh[t]);
}

// ---------------------------------------------------------------------------
// transpose x[k][h][w] -> xt[(w*H+h)*128 + k]
// ---------------------------------------------------------------------------
__global__ __launch_bounds__(256) void transpose_k(const float* __restrict__ X,
                                                   float* __restrict__ xt) {
  __shared__ float tile[32][33];
  const int w0 = (blockIdx.x & 7) * 32;
  const int k0 = ((blockIdx.x >> 3) & 3) * 32;
  const int h  = blockIdx.x >> 5;
  const int t = threadIdx.x;
  const int c = t & 31, rr = t >> 5;
#pragma unroll
  for (int j = 0; j < 4; ++j) {
    const int k = rr + j * 8;
    tile[k][c] = X[(k0 + k) * NPIX + h * W_ + w0 + c];
  }
  __syncthreads();
#pragma unroll
  for (int j = 0; j < 4; ++j) {
    const int w = rr + j * 8;
    xt[((w0 + w) * H_ + h) * 128 + k0 + c] = tile[c][w];
  }
}

// parallel scan + descriptor emit
template<int NB>
__global__ __launch_bounds__(256) void scan_desc_k(const int* __restrict__ cnt,
    int* __restrict__ off, int* __restrict__ desc, int* __restrict__ ndesc) {
  const int t = threadIdx.x;
  const int lane = t & 63, wvi = t >> 6;
  __shared__ int wsumC[4], wsumD[4];
  const int c = (t < NB) ? cnt[t] : 0;
  const int nb = (c + TPB - 1) / TPB;
  int ic = c, id = nb;
  for (int d = 1; d < 64; d <<= 1) {
    const int uc = __shfl_up(ic, d, 64);
    const int ud = __shfl_up(id, d, 64);
    if (lane >= d) { ic += uc; id += ud; }
  }
  if (lane == 63) { wsumC[wvi] = ic; wsumD[wvi] = id; }
  __syncthreads();
  int bc = 0, bd = 0;
#pragma unroll
  for (int w2 = 0; w2 < 4; ++w2) {
    if (w2 < wvi) { bc += wsumC[w2]; bd += wsumD[w2]; }
  }
  ic += bc; id += bd;
  if (t < NB) {
    off[t] = ic - c;
    const int db = id - nb;
    for (int j = 0; j < nb; ++j) desc[db + j] = (t << 12) | j;
  }
  if (t == NB - 1) *ndesc = id;
}

// two-level scatter
template<typename T>
__global__ __launch_bounds__(256) void scatter_k(const T* __restrict__ bins,
    const int* __restrict__ off, int* __restrict__ cursor,
    int* __restrict__ ord, int nbins) {
  __shared__ int lhist[256], lbase[256], lcur[256];
  const int t = threadIdx.x;
  const int n = blockIdx.x * 256 + t;
  if (t < nbins) { lhist[t] = 0; lcur[t] = 0; }
  __syncthreads();
  const int b = (int)bins[n];
  atomicAdd(&lhist[b], 1);
  __syncthreads();
  if (t < nbins && lhist[t] > 0) lbase[t] = atomicAdd(&cursor[t], lhist[t]);
  __syncthreads();
  const int r = atomicAdd(&lcur[b], 1);
  ord[off[b] + lbase[b] + r] = n;
}

// ---------------------------------------------------------------------------
// chain1 v5 (unchanged): LDS-staged expert weights + x rows; pure-LDS k-loop.
// ---------------------------------------------------------------------------
__global__ __launch_bounds__(256) void chain1_k(const float* __restrict__ xt,
    const int* __restrict__ ord1, const int* __restrict__ off1,
    const int* __restrict__ cnt1, const int* __restrict__ desc1,
    const int* __restrict__ nd1,
    const float* __restrict__ wc21, const float* __restrict__ bc21,
    const float* __restrict__ wc22, const float* __restrict__ bc22,
    const float* __restrict__ wc23, const float* __restrict__ bc23,
    int* __restrict__ e12a, int* __restrict__ cnt2) {
  if ((int)blockIdx.x >= *nd1) return;
  __shared__ float w1s[4096];
  __shared__ float w2s[1024];
  __shared__ float w3s[512];
  __shared__ float bs[80];
  __shared__ float xs_[64][132];
  __shared__ int lh[16];
  const int t = threadIdx.x;
  if (t < 16) lh[t] = 0;
  const int tg = t >> 2, sub = t & 3;
  const int l0 = (t & 63) & ~3;
  const int de = desc1[blockIdx.x];
  const int e = de >> 12, chunk = de & 0xFFF;
  const int cnt = cnt1[e];
  const int pos = chunk * TPB + tg;
  const bool valid = pos < cnt;
  const int n = valid ? ord1[off1[e] + pos] : 0;

  {
    const float4* __restrict__ Wg1 = (const float4*)(wc21 + e * 4096);
#pragma unroll
    for (int j = 0; j < 4; ++j)
      *(float4*)&w1s[t * 4 + j * 1024] = Wg1[t + j * 256];
    const float4* __restrict__ Wg2 = (const float4*)(wc22 + e * 1024);
    *(float4*)&w2s[t * 4] = Wg2[t];
    if (t < 128) {
      const float4* __restrict__ Wg3 = (const float4*)(wc23 + e * 512);
      *(float4*)&w3s[t * 4] = Wg3[t];
    }
    if (t < 32) bs[t] = bc21[e * 32 + t];
    else if (t < 64) bs[t] = bc22[e * 32 + (t - 32)];
    else if (t < 80) bs[t] = bc23[e * 16 + (t - 64)];
  }
  {
    const float4* __restrict__ src = (const float4*)(xt + n * 128 + sub * 32);
    float4 tmp[8];
#pragma unroll
    for (int j = 0; j < 8; ++j) tmp[j] = src[j];
#pragma unroll
    for (int j = 0; j < 8; ++j)
      *(float4*)(&xs_[tg][sub * 32 + 4 * j]) = tmp[j];
  }
  __syncthreads();

  const int wb1 = sub * 8;
  float a[8];
#pragma unroll
  for (int o = 0; o < 8; ++o) a[o] = bs[wb1 + o];
#pragma unroll
  for (int k = 0; k < 128; k += 4) {
    float x4[4];
    *(float4*)x4 = *(const float4*)(&xs_[tg][k]);
#pragma unroll
    for (int kk = 0; kk < 4; ++kk) {
      float w8[8];
      *(float4*)&w8[0] = *(const float4*)&w1s[(k + kk) * 32 + wb1];
      *(float4*)&w8[4] = *(const float4*)&w1s[(k + kk) * 32 + wb1 + 4];
#pragma unroll
      for (int o = 0; o < 8; ++o) a[o] = fmaf(x4[kk], w8[o], a[o]);
    }
  }
#pragma unroll
  for (int o = 0; o < 8; ++o) a[o] = a[o] > 0.f ? a[o] : 0.01f * a[o];

  float b[8];
#pragma unroll
  for (int o = 0; o < 8; ++o) b[o] = bs[32 + wb1 + o];
#pragma unroll
  for (int i = 0; i < 32; ++i) {
    const float hv = __shfl(a[i & 7], l0 + (i >> 3), 64);
    float w8[8];
    *(float4*)&w8[0] = *(const float4*)&w2s[i * 32 + wb1];
    *(float4*)&w8[4] = *(const float4*)&w2s[i * 32 + wb1 + 4];
#pragma unroll
    for (int o = 0; o < 8; ++o) b[o] = fmaf(hv, w8[o], b[o]);
  }
#pragma unroll
  for (int o = 0; o < 8; ++o) b[o] = b[o] > 0.f ? b[o] : 0.01f * b[o];

  float s[4];
#pragma unroll
  for (int j = 0; j < 4; ++j) s[j] = bs[64 + sub * 4 + j];
#pragma unroll
  for (int i = 0; i < 32; ++i) {
    const float hv = __shfl(b[i & 7], l0 + (i >> 3), 64);
    float w4[4];
    *(float4*)w4 = *(const float4*)&w3s[i * 16 + sub * 4];
#pragma unroll
    for (int j = 0; j < 4; ++j) s[j] = fmaf(hv, w4[j], s[j]);
  }

  float bv = s[0];
  int bi = sub * 4;
#pragma unroll
  for (int j = 1; j < 4; ++j) {
    if (s[j] > bv) { bv = s[j]; bi = sub * 4 + j; }
  }
#pragma unroll
  for (int d = 1; d < 4; d <<= 1) {
    const float ov = __shfl_xor(bv, d, 64);
    const int oi = __shfl_xor(bi, d, 64);
    if (ov > bv || (ov == bv && oi < bi)) { bv = ov; bi = oi; }
  }
  const int e12 = e * 16 + bi;
  if (valid && sub == 0) {
    e12a[n] = e12;
    atomicAdd(&lh[bi], 1);
  }
  __syncthreads();
  if (t < 16 && lh[t] > 0)
    atomicAdd(&cnt2[e * 16 + t], lh[t]);
}

// ---------------------------------------------------------------------------
// chain2 v5 (unchanged): LDS-weight-staged. Writes out[n].
// ---------------------------------------------------------------------------
__global__ __launch_bounds__(256) void chain2_k(const float* __restrict__ xt,
    const int* __restrict__ ord2, const int* __restrict__ off2,
    const int* __restrict__ cnt2, const int* __restrict__ desc2,
    const int* __restrict__ nd2,
    const float* __restrict__ wr11, const float* __restrict__ br11,
    const float* __restrict__ wr12, const float* __restrict__ br12,
    const float* __restrict__ wr13, const float* __restrict__ br13,
    float* __restrict__ out) {
  if ((int)blockIdx.x >= *nd2) return;
  __shared__ float w1s[4096];
  __shared__ float w2s[512];
  __shared__ float w3s[16];
  __shared__ float bs[49];
  __shared__ float xs_[64][132];
  const int t = threadIdx.x;
  const int tg = t >> 2, sub = t & 3;
  const int l0 = (t & 63) & ~3;
  const int de = desc2[blockIdx.x];
  const int e12 = de >> 12, chunk = de & 0xFFF;
  const int cnt = cnt2[e12];
  const int pos = chunk * TPB + tg;
  const bool valid = pos < cnt;
  const int n = valid ? ord2[off2[e12] + pos] : 0;

  {
    const float4* __restrict__ Wg1 = (const float4*)(wr11 + e12 * 4096);
#pragma unroll
    for (int j = 0; j < 4; ++j)
      *(float4*)&w1s[t * 4 + j * 1024] = Wg1[t + j * 256];
    if (t < 128) {
      const float4* __restrict__ Wg2 = (const float4*)(wr12 + e12 * 512);
      *(float4*)&w2s[t * 4] = Wg2[t];
    }
    if (t < 16) w3s[t] = wr13[e12 * 16 + t];
    if (t < 32) bs[t] = br11[e12 * 32 + t];
    else if (t < 48) bs[t] = br12[e12 * 16 + (t - 32)];
    else if (t == 48) bs[48] = br13[e12];
  }
  {
    const float4* __restrict__ src = (const float4*)(xt + n * 128 + sub * 32);
    float4 tmp[8];
#pragma unroll
    for (int j = 0; j < 8; ++j) tmp[j] = src[j];
#pragma unroll
    for (int j = 0; j < 8; ++j)
      *(float4*)(&xs_[tg][sub * 32 + 4 * j]) = tmp[j];
  }
  __syncthreads();

  const int wb1 = sub * 8;
  float a[8];
#pragma unroll
  for (int o = 0; o < 8; ++o) a[o] = bs[wb1 + o];
#pragma unroll
  for (int k = 0; k < 128; k += 4) {
    float x4[4];
    *(float4*)x4 = *(const float4*)(&xs_[tg][k]);
#pragma unroll
    for (int kk = 0; kk < 4; ++kk) {
      float w8[8];
      *(float4*)&w8[0] = *(const float4*)&w1s[(k + kk) * 32 + wb1];
      *(float4*)&w8[4] = *(const float4*)&w1s[(k + kk) * 32 + wb1 + 4];
#pragma unroll
      for (int o = 0; o < 8; ++o) a[o] = fmaf(x4[kk], w8[o], a[o]);
    }
  }
#pragma unroll
  for (int o = 0; o < 8; ++o) a[o] = a[o] > 0.f ? a[o] : 0.01f * a[o];

  float s[4];
#pragma unroll
  for (int j = 0; j < 4; ++j) s[j] = bs[32 + sub * 4 + j];
#pragma unroll
  for (int i = 0; i < 32; ++i) {
    const float hv = __shfl(a[i & 7], l0 + (i >> 3), 64);
    float w4[4];
    *(float4*)w4 = *(const float4*)&w2s[i * 16 + sub * 4];
#pragma unroll
    for (int j = 0; j < 4; ++j) s[j] = fmaf(hv, w4[j], s[j]);
  }
#pragma unroll
  for (int j = 0; j < 4; ++j) s[j] = s[j] > 0.f ? s[j] : 0.01f * s[j];

  float r = bs[48];
#pragma unroll
  for (int i = 0; i < 16; ++i) {
    const float hv = __shfl(s[i & 3], l0 + (i >> 2), 64);
    r = fmaf(hv, w3s[i], r);
  }

  if (valid && sub == 0) out[n] = ((float)e12 + r) * (1.0f / 256.0f);
}

// ---------------------------------------------------------------------------
extern "C" void kernel_launch(void* const* d_in, const int* in_sizes, int n_in,
                              void* d_out, int out_size, void* d_ws,
                              size_t ws_size, hipStream_t stream) {
  const float* x_in  = (const float*)d_in[0];
  const float* w_c11 = (const float*)d_in[1];
  const float* b_c11 = (const float*)d_in[2];
  const float* w_c12 = (const float*)d_in[3];
  const float* b_c12 = (const float*)d_in[4];
  const float* w_c13 = (const float*)d_in[5];
  const float* b_c13 = (const float*)d_in[6];
  const float* w_c21 = (const float*)d_in[7];
  const float* b_c21 = (const float*)d_in[8];
  const float* w_c22 = (const float*)d_in[9];
  const float* b_c22 = (const float*)d_in[10];
  const float* w_c23 = (const float*)d_in[11];
  const float* b_c23 = (const float*)d_in[12];
  const float* w_r11 = (const float*)d_in[13];
  const float* b_r11 = (const float*)d_in[14];
  const float* w_r12 = (const float*)d_in[15];
  const float* b_r12 = (const float*)d_in[16];
  const float* w_r13 = (const float*)d_in[17];
  const float* b_r13 = (const float*)d_in[18];

  float* out = (float*)d_out;   // [0..N): x_real (token order), [N..2N): mask

  float* R0 = (float*)d_ws;
  float* R1 = R0 + 128 * NPIX;
  float* R2 = R1 + 128 * NPIX;

  float* xt = R0;
  unsigned char* inds1 = (unsigned char*)R2;   // N bytes
  float* wT1 = R2 + 12288;
  float* wT2 = wT1 + 16384;
  int* S = (int*)R2 + 45056;

  int* cnt1  = S;            // 16
  int* cur1  = S + 16;       // 16
  int* off1  = S + 32;       // 16
  int* nd1   = S + 48;       // 1 (+pad)
  int* desc1 = S + 64;       // 1024
  int* cnt2  = S + 1088;     // 256
  int* cur2  = S + 1344;     // 256
  int* off2  = S + 1600;     // 256
  int* nd2   = S + 1856;     // 1 (+pad)
  int* desc2 = S + 1872;     // 1024

  int* ib   = (int*)R1;
  int* ord1 = ib;            // N
  int* ord2 = ib + NPIX;     // N
  int* e12a = ib + 2 * NPIX; // N

  wtrans2_k<<<32, 256, 0, stream>>>(w_c11, wT1, w_c12, wT2, S);
  convfused_k<<<NPIX / 32, 128, 0, stream>>>(x_in, wT1, b_c11, wT2, b_c12,
      w_c13, b_c13, inds1, out + NPIX, cnt1);
  transpose_k<<<192 * 32, 256, 0, stream>>>(x_in, xt);
  scan_desc_k<16><<<1, 256, 0, stream>>>(cnt1, off1, desc1, nd1);
  scatter_k<unsigned char><<<NPIX / 256, 256, 0, stream>>>(inds1, off1, cur1,
                                                           ord1, 16);
  chain1_k<<<NPIX / TPB + 16, 256, 0, stream>>>(xt, ord1, off1, cnt1, desc1,
      nd1, w_c21, b_c21, w_c22, b_c22, w_c23, b_c23, e12a, cnt2);
  scan_desc_k<256><<<1, 256, 0, stream>>>(cnt2, off2, desc2, nd2);
  scatter_k<int><<<NPIX / 256, 256, 0, stream>>>(e12a, off2, cur2, ord2, 256);
  chain2_k<<<NPIX / TPB + 256, 256, 0, stream>>>(xt, ord2, off2, cnt2, desc2,
      nd2, w_r11, b_r11, w_r12, b_r12, w_r13, b_r13, out);
}

// Round 10
// 165.878 us; speedup vs baseline: 1.5146x; 1.0389x over previous
//
#include <hip/hip_runtime.h>

#define NPIX 49152   // B*H*W = 1*192*256
#define H_ 192
#define W_ 256
#define TPB 64       // tokens per chain block (64 tokens x 4 lanes = 256 thr)

// ---------------------------------------------------------------------------
// both weight transposes (32 blocks) + zero binning counters (block 0)
// ---------------------------------------------------------------------------
__global__ __launch_bounds__(256) void wtrans2_k(const float* __restrict__ Wa,
    float* __restrict__ WTa, const float* __restrict__ Wb,
    float* __restrict__ WTb, int* __restrict__ S) {
  const int b = blockIdx.x;
  const float* __restrict__ W = (b < 16) ? Wa : Wb;
  float* __restrict__ WT = (b < 16) ? WTa : WTb;
  const int bb = b & 15;
  __shared__ float tile[32][33];
  const int bx = bb & 3, by = bb >> 2;
  const int c = threadIdx.x & 31, r0 = threadIdx.x >> 5;
#pragma unroll
  for (int j = 0; j < 4; ++j) {
    const int r = r0 + j * 8;
    tile[r][c] = W[(by * 32 + r) * 128 + bx * 32 + c];
  }
  __syncthreads();
#pragma unroll
  for (int j = 0; j < 4; ++j) {
    const int r = r0 + j * 8;
    WT[(bx * 32 + r) * 128 + by * 32 + c] = tile[c][r];
  }
  if (b == 0) {
    const int t = threadIdx.x;
    if (t < 32) S[t] = 0;        // cnt1 + cur1
    S[1088 + t] = 0;             // cnt2
    S[1344 + t] = 0;             // cur2
  }
}

// ---------------------------------------------------------------------------
// FUSED conv1 + conv2 + conv17 + argmax + mask + histogram + x transpose.
// One barrier per chunk (true double-buffer: compute reads cur, stage writes
// nxt — disjoint). Phase 1 also emits xt rows from the staged raw X.
// Per-output FMA chains (bias then k ascending) bitwise identical to before.
// ---------------------------------------------------------------------------
__global__ __launch_bounds__(128) void convfused_k(const float* __restrict__ X,
    const float* __restrict__ WT1, const float* __restrict__ Bv1,
    const float* __restrict__ WT2, const float* __restrict__ Bv2,
    const float* __restrict__ W3, const float* __restrict__ Bv3,
    unsigned char* __restrict__ inds1, float* __restrict__ mask_out,
    int* __restrict__ cnt1, float* __restrict__ xt) {
  __shared__ float xb[2][16][32];     // 4 KB   phase-1 X staging (raw X)
  __shared__ float wpool[2][16][128]; // 16 KB  W staging; later W3 [k][20]
  __shared__ float xs2[128][36];      // 18 KB  inter-phase activations
  __shared__ int lh[16];
  const int t = threadIdx.x;
  const int p0 = blockIdx.x * 32;
  const int to = t >> 3;              // 0..15: outputs to*8..to*8+7
  const int tp = t & 7;               // 0..7 : pixels  tp*4..tp*4+3
  const int wcol = to * 8;
  if (t < 16) lh[t] = 0;

  // xt destination for the transpose side-channel
  const int px = t >> 2, q = t & 3;   // pixel 0..31, k-quarter 0..3
  const int pglob = p0 + px;
  float* __restrict__ xtp = xt + ((pglob & 255) * H_ + (pglob >> 8)) * 128;

  float acc[8][4];

  // ================= PHASE 1: conv1 (X global, W1 LDS) =================
#pragma unroll
  for (int i = 0; i < 8; ++i) {
    const float b = Bv1[to * 8 + i];
#pragma unroll
    for (int j = 0; j < 4; ++j) acc[i][j] = b;
  }
  {
    const int k = t >> 3, c = (t & 7) * 4;
    *(float4*)(&xb[0][k][c]) = *(const float4*)(X + k * NPIX + p0 + c);
  }
#pragma unroll
  for (int j = 0; j < 4; ++j) {
    const int idx = t + j * 128, k = idx >> 5, c = (idx & 31) * 4;
    *(float4*)(&wpool[0][k][c]) = *(const float4*)(WT1 + k * 128 + c);
  }
  __syncthreads();

  for (int ch = 0; ch < 8; ++ch) {
    const int cur = ch & 1, nxt = cur ^ 1;
    float4 xs, ws[4];
    const int k1 = (ch + 1) * 16;
    if (ch < 7) {
      {
        const int k = t >> 3, c = (t & 7) * 4;
        xs = *(const float4*)(X + (k1 + k) * NPIX + p0 + c);
      }
#pragma unroll
      for (int j = 0; j < 4; ++j) {
        const int idx = t + j * 128, k = idx >> 5, c = (idx & 31) * 4;
        ws[j] = *(const float4*)(WT1 + (k1 + k) * 128 + c);
      }
    }
    // transpose side-channel: xt[n][ch*16 + q*4 .. +3] from staged raw X
    {
      float tx[4];
#pragma unroll
      for (int j = 0; j < 4; ++j) tx[j] = xb[cur][q * 4 + j][px];
      *(float4*)(xtp + ch * 16 + q * 4) = *(float4*)tx;
    }
#pragma unroll
    for (int k = 0; k < 16; ++k) {
      float xv[4], wv[8];
      *(float4*)&xv[0] = *(const float4*)(&xb[cur][k][tp * 4]);
      *(float4*)&wv[0] = *(const float4*)(&wpool[cur][k][wcol]);
      *(float4*)&wv[4] = *(const float4*)(&wpool[cur][k][wcol + 4]);
#pragma unroll
      for (int i = 0; i < 8; ++i)
#pragma unroll
        for (int j = 0; j < 4; ++j)
          acc[i][j] = fmaf(wv[i], xv[j], acc[i][j]);
    }
    if (ch < 7) {
      {
        const int k = t >> 3, c = (t & 7) * 4;
        *(float4*)(&xb[nxt][k][c]) = xs;
      }
#pragma unroll
      for (int j = 0; j < 4; ++j) {
        const int idx = t + j * 128, k = idx >> 5, c = (idx & 31) * 4;
        *(float4*)(&wpool[nxt][k][c]) = ws[j];
      }
      __syncthreads();   // single barrier per chunk
    }
  }

  // epilogue 1: lrelu -> xs2; stage W2 chunk 0 into wpool[0].
  // (safe unsynced: peer waves in chunk 7 read xb[1]/wpool[1] only)
#pragma unroll
  for (int i = 0; i < 8; ++i) {
    float v[4];
#pragma unroll
    for (int j = 0; j < 4; ++j) {
      const float x = acc[i][j];
      v[j] = x > 0.f ? x : 0.01f * x;
    }
    *(float4*)(&xs2[to * 8 + i][tp * 4]) = *(float4*)v;
  }
#pragma unroll
  for (int j = 0; j < 4; ++j) {
    const int idx = t + j * 128, k = idx >> 5, c = (idx & 31) * 4;
    *(float4*)(&wpool[0][k][c]) = *(const float4*)(WT2 + k * 128 + c);
  }
  __syncthreads();

  // ================= PHASE 2: conv2 (x from xs2, W2 LDS) =================
#pragma unroll
  for (int i = 0; i < 8; ++i) {
    const float b = Bv2[to * 8 + i];
#pragma unroll
    for (int j = 0; j < 4; ++j) acc[i][j] = b;
  }
  for (int ch = 0; ch < 8; ++ch) {
    const int cur = ch & 1, nxt = cur ^ 1;
    float4 ws[4];
    const int k1 = (ch + 1) * 16;
    if (ch < 7) {
#pragma unroll
      for (int j = 0; j < 4; ++j) {
        const int idx = t + j * 128, k = idx >> 5, c = (idx & 31) * 4;
        ws[j] = *(const float4*)(WT2 + (k1 + k) * 128 + c);
      }
    }
    const int k0 = ch * 16;
#pragma unroll
    for (int k = 0; k < 16; ++k) {
      float xv[4], wv[8];
      *(float4*)&xv[0] = *(const float4*)(&xs2[k0 + k][tp * 4]);
      *(float4*)&wv[0] = *(const float4*)(&wpool[cur][k][wcol]);
      *(float4*)&wv[4] = *(const float4*)(&wpool[cur][k][wcol + 4]);
#pragma unroll
      for (int i = 0; i < 8; ++i)
#pragma unroll
        for (int j = 0; j < 4; ++j)
          acc[i][j] = fmaf(wv[i], xv[j], acc[i][j]);
    }
    if (ch < 7) {
#pragma unroll
      for (int j = 0; j < 4; ++j) {
        const int idx = t + j * 128, k = idx >> 5, c = (idx & 31) * 4;
        *(float4*)(&wpool[nxt][k][c]) = ws[j];
      }
      __syncthreads();   // single barrier per chunk
    }
  }

  // all waves must finish phase-2 reads of xs2/wpool before overwriting
  __syncthreads();

  // epilogue 2: lrelu -> xs2 ; stage W3 as w3s[k][20] across wpool
  float* w3s = &wpool[0][0][0];
#pragma unroll
  for (int i = 0; i < 8; ++i) {
    float v[4];
#pragma unroll
    for (int j = 0; j < 4; ++j) {
      const float x = acc[i][j];
      v[j] = x > 0.f ? x : 0.01f * x;
    }
    *(float4*)(&xs2[to * 8 + i][tp * 4]) = *(float4*)v;
  }
  for (int i = t; i < 17 * 128; i += 128)
    w3s[(i & 127) * 20 + (i >> 7)] = W3[i];
  __syncthreads();

  // ================= PHASE 3: conv17 + argmax + mask + hist =============
  {
    const int p = px, sub = q;               // 4 lanes per pixel
    float s4[4];
#pragma unroll
    for (int j = 0; j < 4; ++j) s4[j] = Bv3[sub * 4 + j];
    float m = Bv3[16];
#pragma unroll 8
    for (int k = 0; k < 128; ++k) {
      const float xv = xs2[k][p];
      float w4[4];
      *(float4*)w4 = *(const float4*)&w3s[k * 20 + sub * 4];
#pragma unroll
      for (int j = 0; j < 4; ++j) s4[j] = fmaf(xv, w4[j], s4[j]);
      m = fmaf(xv, w3s[k * 20 + 16], m);
    }
    // argmax over 16: per-lane first-max-wins, then min-index-of-max combine
    float bv = s4[0];
    int bi = sub * 4;
#pragma unroll
    for (int j = 1; j < 4; ++j) {
      if (s4[j] > bv) { bv = s4[j]; bi = sub * 4 + j; }
    }
#pragma unroll
    for (int d = 1; d < 4; d <<= 1) {
      const float ov = __shfl_xor(bv, d, 64);
      const int oi = __shfl_xor(bi, d, 64);
      if (ov > bv || (ov == bv && oi < bi)) { bv = ov; bi = oi; }
    }
    if (sub == 0) {
      inds1[p0 + p] = (unsigned char)bi;
      mask_out[p0 + p] = m > 0.f ? m : 0.01f * m;
      atomicAdd(&lh[bi], 1);
    }
  }
  __syncthreads();
  if (t < 16 && lh[t] > 0) atomicAdd(&cnt1[t], lh[t]);
}

// parallel scan + descriptor emit
template<int NB>
__global__ __launch_bounds__(256) void scan_desc_k(const int* __restrict__ cnt,
    int* __restrict__ off, int* __restrict__ desc, int* __restrict__ ndesc) {
  const int t = threadIdx.x;
  const int lane = t & 63, wvi = t >> 6;
  __shared__ int wsumC[4], wsumD[4];
  const int c = (t < NB) ? cnt[t] : 0;
  const int nb = (c + TPB - 1) / TPB;
  int ic = c, id = nb;
  for (int d = 1; d < 64; d <<= 1) {
    const int uc = __shfl_up(ic, d, 64);
    const int ud = __shfl_up(id, d, 64);
    if (lane >= d) { ic += uc; id += ud; }
  }
  if (lane == 63) { wsumC[wvi] = ic; wsumD[wvi] = id; }
  __syncthreads();
  int bc = 0, bd = 0;
#pragma unroll
  for (int w2 = 0; w2 < 4; ++w2) {
    if (w2 < wvi) { bc += wsumC[w2]; bd += wsumD[w2]; }
  }
  ic += bc; id += bd;
  if (t < NB) {
    off[t] = ic - c;
    const int db = id - nb;
    for (int j = 0; j < nb; ++j) desc[db + j] = (t << 12) | j;
  }
  if (t == NB - 1) *ndesc = id;
}

// two-level scatter
template<typename T>
__global__ __launch_bounds__(256) void scatter_k(const T* __restrict__ bins,
    const int* __restrict__ off, int* __restrict__ cursor,
    int* __restrict__ ord, int nbins) {
  __shared__ int lhist[256], lbase[256], lcur[256];
  const int t = threadIdx.x;
  const int n = blockIdx.x * 256 + t;
  if (t < nbins) { lhist[t] = 0; lcur[t] = 0; }
  __syncthreads();
  const int b = (int)bins[n];
  atomicAdd(&lhist[b], 1);
  __syncthreads();
  if (t < nbins && lhist[t] > 0) lbase[t] = atomicAdd(&cursor[t], lhist[t]);
  __syncthreads();
  const int r = atomicAdd(&lcur[b], 1);
  ord[off[b] + lbase[b] + r] = n;
}

// ---------------------------------------------------------------------------
// chain1 v5 (unchanged): LDS-staged expert weights + x rows; pure-LDS k-loop.
// ---------------------------------------------------------------------------
__global__ __launch_bounds__(256) void chain1_k(const float* __restrict__ xt,
    const int* __restrict__ ord1, const int* __restrict__ off1,
    const int* __restrict__ cnt1, const int* __restrict__ desc1,
    const int* __restrict__ nd1,
    const float* __restrict__ wc21, const float* __restrict__ bc21,
    const float* __restrict__ wc22, const float* __restrict__ bc22,
    const float* __restrict__ wc23, const float* __restrict__ bc23,
    int* __restrict__ e12a, int* __restrict__ cnt2) {
  if ((int)blockIdx.x >= *nd1) return;
  __shared__ float w1s[4096];
  __shared__ float w2s[1024];
  __shared__ float w3s[512];
  __shared__ float bs[80];
  __shared__ float xs_[64][132];
  __shared__ int lh[16];
  const int t = threadIdx.x;
  if (t < 16) lh[t] = 0;
  const int tg = t >> 2, sub = t & 3;
  const int l0 = (t & 63) & ~3;
  const int de = desc1[blockIdx.x];
  const int e = de >> 12, chunk = de & 0xFFF;
  const int cnt = cnt1[e];
  const int pos = chunk * TPB + tg;
  const bool valid = pos < cnt;
  const int n = valid ? ord1[off1[e] + pos] : 0;

  {
    const float4* __restrict__ Wg1 = (const float4*)(wc21 + e * 4096);
#pragma unroll
    for (int j = 0; j < 4; ++j)
      *(float4*)&w1s[t * 4 + j * 1024] = Wg1[t + j * 256];
    const float4* __restrict__ Wg2 = (const float4*)(wc22 + e * 1024);
    *(float4*)&w2s[t * 4] = Wg2[t];
    if (t < 128) {
      const float4* __restrict__ Wg3 = (const float4*)(wc23 + e * 512);
      *(float4*)&w3s[t * 4] = Wg3[t];
    }
    if (t < 32) bs[t] = bc21[e * 32 + t];
    else if (t < 64) bs[t] = bc22[e * 32 + (t - 32)];
    else if (t < 80) bs[t] = bc23[e * 16 + (t - 64)];
  }
  {
    const float4* __restrict__ src = (const float4*)(xt + n * 128 + sub * 32);
    float4 tmp[8];
#pragma unroll
    for (int j = 0; j < 8; ++j) tmp[j] = src[j];
#pragma unroll
    for (int j = 0; j < 8; ++j)
      *(float4*)(&xs_[tg][sub * 32 + 4 * j]) = tmp[j];
  }
  __syncthreads();

  const int wb1 = sub * 8;
  float a[8];
#pragma unroll
  for (int o = 0; o < 8; ++o) a[o] = bs[wb1 + o];
#pragma unroll
  for (int k = 0; k < 128; k += 4) {
    float x4[4];
    *(float4*)x4 = *(const float4*)(&xs_[tg][k]);
#pragma unroll
    for (int kk = 0; kk < 4; ++kk) {
      float w8[8];
      *(float4*)&w8[0] = *(const float4*)&w1s[(k + kk) * 32 + wb1];
      *(float4*)&w8[4] = *(const float4*)&w1s[(k + kk) * 32 + wb1 + 4];
#pragma unroll
      for (int o = 0; o < 8; ++o) a[o] = fmaf(x4[kk], w8[o], a[o]);
    }
  }
#pragma unroll
  for (int o = 0; o < 8; ++o) a[o] = a[o] > 0.f ? a[o] : 0.01f * a[o];

  float b[8];
#pragma unroll
  for (int o = 0; o < 8; ++o) b[o] = bs[32 + wb1 + o];
#pragma unroll
  for (int i = 0; i < 32; ++i) {
    const float hv = __shfl(a[i & 7], l0 + (i >> 3), 64);
    float w8[8];
    *(float4*)&w8[0] = *(const float4*)&w2s[i * 32 + wb1];
    *(float4*)&w8[4] = *(const float4*)&w2s[i * 32 + wb1 + 4];
#pragma unroll
    for (int o = 0; o < 8; ++o) b[o] = fmaf(hv, w8[o], b[o]);
  }
#pragma unroll
  for (int o = 0; o < 8; ++o) b[o] = b[o] > 0.f ? b[o] : 0.01f * b[o];

  float s[4];
#pragma unroll
  for (int j = 0; j < 4; ++j) s[j] = bs[64 + sub * 4 + j];
#pragma unroll
  for (int i = 0; i < 32; ++i) {
    const float hv = __shfl(b[i & 7], l0 + (i >> 3), 64);
    float w4[4];
    *(float4*)w4 = *(const float4*)&w3s[i * 16 + sub * 4];
#pragma unroll
    for (int j = 0; j < 4; ++j) s[j] = fmaf(hv, w4[j], s[j]);
  }

  float bv = s[0];
  int bi = sub * 4;
#pragma unroll
  for (int j = 1; j < 4; ++j) {
    if (s[j] > bv) { bv = s[j]; bi = sub * 4 + j; }
  }
#pragma unroll
  for (int d = 1; d < 4; d <<= 1) {
    const float ov = __shfl_xor(bv, d, 64);
    const int oi = __shfl_xor(bi, d, 64);
    if (ov > bv || (ov == bv && oi < bi)) { bv = ov; bi = oi; }
  }
  const int e12 = e * 16 + bi;
  if (valid && sub == 0) {
    e12a[n] = e12;
    atomicAdd(&lh[bi], 1);
  }
  __syncthreads();
  if (t < 16 && lh[t] > 0)
    atomicAdd(&cnt2[e * 16 + t], lh[t]);
}

// ---------------------------------------------------------------------------
// chain2 v5 (unchanged): LDS-weight-staged. Writes out[n].
// ---------------------------------------------------------------------------
__global__ __launch_bounds__(256) void chain2_k(const float* __restrict__ xt,
    const int* __restrict__ ord2, const int* __restrict__ off2,
    const int* __restrict__ cnt2, const int* __restrict__ desc2,
    const int* __restrict__ nd2,
    const float* __restrict__ wr11, const float* __restrict__ br11,
    const float* __restrict__ wr12, const float* __restrict__ br12,
    const float* __restrict__ wr13, const float* __restrict__ br13,
    float* __restrict__ out) {
  if ((int)blockIdx.x >= *nd2) return;
  __shared__ float w1s[4096];
  __shared__ float w2s[512];
  __shared__ float w3s[16];
  __shared__ float bs[49];
  __shared__ float xs_[64][132];
  const int t = threadIdx.x;
  const int tg = t >> 2, sub = t & 3;
  const int l0 = (t & 63) & ~3;
  const int de = desc2[blockIdx.x];
  const int e12 = de >> 12, chunk = de & 0xFFF;
  const int cnt = cnt2[e12];
  const int pos = chunk * TPB + tg;
  const bool valid = pos < cnt;
  const int n = valid ? ord2[off2[e12] + pos] : 0;

  {
    const float4* __restrict__ Wg1 = (const float4*)(wr11 + e12 * 4096);
#pragma unroll
    for (int j = 0; j < 4; ++j)
      *(float4*)&w1s[t * 4 + j * 1024] = Wg1[t + j * 256];
    if (t < 128) {
      const float4* __restrict__ Wg2 = (const float4*)(wr12 + e12 * 512);
      *(float4*)&w2s[t * 4] = Wg2[t];
    }
    if (t < 16) w3s[t] = wr13[e12 * 16 + t];
    if (t < 32) bs[t] = br11[e12 * 32 + t];
    else if (t < 48) bs[t] = br12[e12 * 16 + (t - 32)];
    else if (t == 48) bs[48] = br13[e12];
  }
  {
    const float4* __restrict__ src = (const float4*)(xt + n * 128 + sub * 32);
    float4 tmp[8];
#pragma unroll
    for (int j = 0; j < 8; ++j) tmp[j] = src[j];
#pragma unroll
    for (int j = 0; j < 8; ++j)
      *(float4*)(&xs_[tg][sub * 32 + 4 * j]) = tmp[j];
  }
  __syncthreads();

  const int wb1 = sub * 8;
  float a[8];
#pragma unroll
  for (int o = 0; o < 8; ++o) a[o] = bs[wb1 + o];
#pragma unroll
  for (int k = 0; k < 128; k += 4) {
    float x4[4];
    *(float4*)x4 = *(const float4*)(&xs_[tg][k]);
#pragma unroll
    for (int kk = 0; kk < 4; ++kk) {
      float w8[8];
      *(float4*)&w8[0] = *(const float4*)&w1s[(k + kk) * 32 + wb1];
      *(float4*)&w8[4] = *(const float4*)&w1s[(k + kk) * 32 + wb1 + 4];
#pragma unroll
      for (int o = 0; o < 8; ++o) a[o] = fmaf(x4[kk], w8[o], a[o]);
    }
  }
#pragma unroll
  for (int o = 0; o < 8; ++o) a[o] = a[o] > 0.f ? a[o] : 0.01f * a[o];

  float s[4];
#pragma unroll
  for (int j = 0; j < 4; ++j) s[j] = bs[32 + sub * 4 + j];
#pragma unroll
  for (int i = 0; i < 32; ++i) {
    const float hv = __shfl(a[i & 7], l0 + (i >> 3), 64);
    float w4[4];
    *(float4*)w4 = *(const float4*)&w2s[i * 16 + sub * 4];
#pragma unroll
    for (int j = 0; j < 4; ++j) s[j] = fmaf(hv, w4[j], s[j]);
  }
#pragma unroll
  for (int j = 0; j < 4; ++j) s[j] = s[j] > 0.f ? s[j] : 0.01f * s[j];

  float r = bs[48];
#pragma unroll
  for (int i = 0; i < 16; ++i) {
    const float hv = __shfl(s[i & 3], l0 + (i >> 2), 64);
    r = fmaf(hv, w3s[i], r);
  }

  if (valid && sub == 0) out[n] = ((float)e12 + r) * (1.0f / 256.0f);
}

// ---------------------------------------------------------------------------
extern "C" void kernel_launch(void* const* d_in, const int* in_sizes, int n_in,
                              void* d_out, int out_size, void* d_ws,
                              size_t ws_size, hipStream_t stream) {
  const float* x_in  = (const float*)d_in[0];
  const float* w_c11 = (const float*)d_in[1];
  const float* b_c11 = (const float*)d_in[2];
  const float* w_c12 = (const float*)d_in[3];
  const float* b_c12 = (const float*)d_in[4];
  const float* w_c13 = (const float*)d_in[5];
  const float* b_c13 = (const float*)d_in[6];
  const float* w_c21 = (const float*)d_in[7];
  const float* b_c21 = (const float*)d_in[8];
  const float* w_c22 = (const float*)d_in[9];
  const float* b_c22 = (const float*)d_in[10];
  const float* w_c23 = (const float*)d_in[11];
  const float* b_c23 = (const float*)d_in[12];
  const float* w_r11 = (const float*)d_in[13];
  const float* b_r11 = (const float*)d_in[14];
  const float* w_r12 = (const float*)d_in[15];
  const float* b_r12 = (const float*)d_in[16];
  const float* w_r13 = (const float*)d_in[17];
  const float* b_r13 = (const float*)d_in[18];

  float* out = (float*)d_out;   // [0..N): x_real (token order), [N..2N): mask

  float* R0 = (float*)d_ws;
  float* R1 = R0 + 128 * NPIX;
  float* R2 = R1 + 128 * NPIX;

  float* xt = R0;
  unsigned char* inds1 = (unsigned char*)R2;   // N bytes
  float* wT1 = R2 + 12288;
  float* wT2 = wT1 + 16384;
  int* S = (int*)R2 + 45056;

  int* cnt1  = S;            // 16
  int* cur1  = S + 16;       // 16
  int* off1  = S + 32;       // 16
  int* nd1   = S + 48;       // 1 (+pad)
  int* desc1 = S + 64;       // 1024
  int* cnt2  = S + 1088;     // 256
  int* cur2  = S + 1344;     // 256
  int* off2  = S + 1600;     // 256
  int* nd2   = S + 1856;     // 1 (+pad)
  int* desc2 = S + 1872;     // 1024

  int* ib   = (int*)R1;
  int* ord1 = ib;            // N
  int* ord2 = ib + NPIX;     // N
  int* e12a = ib + 2 * NPIX; // N

  wtrans2_k<<<32, 256, 0, stream>>>(w_c11, wT1, w_c12, wT2, S);
  convfused_k<<<NPIX / 32, 128, 0, stream>>>(x_in, wT1, b_c11, wT2, b_c12,
      w_c13, b_c13, inds1, out + NPIX, cnt1, xt);
  scan_desc_k<16><<<1, 256, 0, stream>>>(cnt1, off1, desc1, nd1);
  scatter_k<unsigned char><<<NPIX / 256, 256, 0, stream>>>(inds1, off1, cur1,
                                                           ord1, 16);
  chain1_k<<<NPIX / TPB + 16, 256, 0, stream>>>(xt, ord1, off1, cnt1, desc1,
      nd1, w_c21, b_c21, w_c22, b_c22, w_c23, b_c23, e12a, cnt2);
  scan_desc_k<256><<<1, 256, 0, stream>>>(cnt2, off2, desc2, nd2);
  scatter_k<int><<<NPIX / 256, 256, 0, stream>>>(e12a, off2, cur2, ord2, 256);
  chain2_k<<<NPIX / TPB + 256, 256, 0, stream>>>(xt, ord2, off2, cnt2, desc2,
      nd2, w_r11, b_r11, w_r12, b_r12, w_r13, b_r13, out);
}

// Round 11
// 159.978 us; speedup vs baseline: 1.5704x; 1.0369x over previous
//
#include <hip/hip_runtime.h>

#define NPIX 49152   // B*H*W = 1*192*256
#define H_ 192
#define W_ 256
#define TPB 64       // tokens per chain block (64 tokens x 4 lanes = 256 thr)

// ---------------------------------------------------------------------------
// both weight transposes (32 blocks) + zero binning counters (block 0)
// ---------------------------------------------------------------------------
__global__ __launch_bounds__(256) void wtrans2_k(const float* __restrict__ Wa,
    float* __restrict__ WTa, const float* __restrict__ Wb,
    float* __restrict__ WTb, int* __restrict__ S) {
  const int b = blockIdx.x;
  const float* __restrict__ W = (b < 16) ? Wa : Wb;
  float* __restrict__ WT = (b < 16) ? WTa : WTb;
  const int bb = b & 15;
  __shared__ float tile[32][33];
  const int bx = bb & 3, by = bb >> 2;
  const int c = threadIdx.x & 31, r0 = threadIdx.x >> 5;
#pragma unroll
  for (int j = 0; j < 4; ++j) {
    const int r = r0 + j * 8;
    tile[r][c] = W[(by * 32 + r) * 128 + bx * 32 + c];
  }
  __syncthreads();
#pragma unroll
  for (int j = 0; j < 4; ++j) {
    const int r = r0 + j * 8;
    WT[(bx * 32 + r) * 128 + by * 32 + c] = tile[c][r];
  }
  if (b == 0) {
    const int t = threadIdx.x;
    if (t < 32) S[t] = 0;        // cnt1 + cur1
    S[1088 + t] = 0;             // cnt2
    S[1344 + t] = 0;             // cur2
  }
}

// ---------------------------------------------------------------------------
// FUSED conv1 + conv2 + conv17 + argmax + mask + histogram + x transpose.
// 256 threads (4 waves) per 32-pixel tile -> 16 waves/CU to hide LDS latency.
// Micro-tile 4 outputs x 4 pixels. One barrier per chunk (double-buffered).
// Per-output FMA chains (bias then k ascending) bitwise identical to before.
// ---------------------------------------------------------------------------
__global__ __launch_bounds__(256) void convfused_k(const float* __restrict__ X,
    const float* __restrict__ WT1, const float* __restrict__ Bv1,
    const float* __restrict__ WT2, const float* __restrict__ Bv2,
    const float* __restrict__ W3, const float* __restrict__ Bv3,
    unsigned char* __restrict__ inds1, float* __restrict__ mask_out,
    int* __restrict__ cnt1, float* __restrict__ xt) {
  __shared__ float xb[2][16][32];     // 4 KB   phase-1 X staging (raw X)
  __shared__ float wpool[2][16][128]; // 16 KB  W staging; later W3 [k][20]
  __shared__ float xs2[128][33];      // 16.9 KB inter-phase activations
  __shared__ int lh[16];
  const int t = threadIdx.x;
  const int p0 = blockIdx.x * 32;
  const int to4 = t >> 3;             // 0..31: outputs to4*4..to4*4+3
  const int tp = t & 7;               // 0..7 : pixels  tp*4..tp*4+3
  const int wcol = to4 * 4;
  if (t < 16) lh[t] = 0;

  // transpose side-channel indices (t < 128 active)
  const int px_ = t & 31;             // pixel 0..31
  const int f4g = t >> 5;             // k-float4 group 0..3 (for t<128)
  const int pglob = p0 + px_;
  float* __restrict__ xtp = xt + ((pglob & 255) * H_ + (pglob >> 8)) * 128;

  float acc[4][4];

  // ================= PHASE 1: conv1 (X global, W1 LDS) =================
#pragma unroll
  for (int i = 0; i < 4; ++i) {
    const float b = Bv1[to4 * 4 + i];
#pragma unroll
    for (int j = 0; j < 4; ++j) acc[i][j] = b;
  }
  if (t < 128) {
    const int k = t >> 3, c = (t & 7) * 4;
    *(float4*)(&xb[0][k][c]) = *(const float4*)(X + k * NPIX + p0 + c);
  }
#pragma unroll
  for (int j = 0; j < 2; ++j) {
    const int idx = t + j * 256, k = idx >> 5, c = (idx & 31) * 4;
    *(float4*)(&wpool[0][k][c]) = *(const float4*)(WT1 + k * 128 + c);
  }
  __syncthreads();

  for (int ch = 0; ch < 8; ++ch) {
    const int cur = ch & 1, nxt = cur ^ 1;
    float4 xs, ws[2];
    const int k1 = (ch + 1) * 16;
    if (ch < 7) {
      if (t < 128) {
        const int k = t >> 3, c = (t & 7) * 4;
        xs = *(const float4*)(X + (k1 + k) * NPIX + p0 + c);
      }
#pragma unroll
      for (int j = 0; j < 2; ++j) {
        const int idx = t + j * 256, k = idx >> 5, c = (idx & 31) * 4;
        ws[j] = *(const float4*)(WT1 + (k1 + k) * 128 + c);
      }
    }
    // transpose side-channel: xt[n][ch*16 + f4g*4 .. +3] from staged raw X
    if (t < 128) {
      float tx[4];
#pragma unroll
      for (int j = 0; j < 4; ++j) tx[j] = xb[cur][f4g * 4 + j][px_];
      *(float4*)(xtp + ch * 16 + f4g * 4) = *(float4*)tx;
    }
#pragma unroll
    for (int k = 0; k < 16; ++k) {
      float xv[4], wv[4];
      *(float4*)&xv[0] = *(const float4*)(&xb[cur][k][tp * 4]);
      *(float4*)&wv[0] = *(const float4*)(&wpool[cur][k][wcol]);
#pragma unroll
      for (int i = 0; i < 4; ++i)
#pragma unroll
        for (int j = 0; j < 4; ++j)
          acc[i][j] = fmaf(wv[i], xv[j], acc[i][j]);
    }
    if (ch < 7) {
      if (t < 128) {
        const int k = t >> 3, c = (t & 7) * 4;
        *(float4*)(&xb[nxt][k][c]) = xs;
      }
#pragma unroll
      for (int j = 0; j < 2; ++j) {
        const int idx = t + j * 256, k = idx >> 5, c = (idx & 31) * 4;
        *(float4*)(&wpool[nxt][k][c]) = ws[j];
      }
      __syncthreads();   // single barrier per chunk
    }
  }

  // epilogue 1: lrelu -> xs2; stage W2 chunk 0 into wpool[0].
  // (safe unsynced: chunk-7 peers read xb[1]/wpool[1]; xs2 unread in phase 1)
#pragma unroll
  for (int i = 0; i < 4; ++i) {
    float v[4];
#pragma unroll
    for (int j = 0; j < 4; ++j) {
      const float x = acc[i][j];
      v[j] = x > 0.f ? x : 0.01f * x;
    }
    *(float4*)(&xs2[to4 * 4 + i][tp * 4]) = *(float4*)v;
  }
#pragma unroll
  for (int j = 0; j < 2; ++j) {
    const int idx = t + j * 256, k = idx >> 5, c = (idx & 31) * 4;
    *(float4*)(&wpool[0][k][c]) = *(const float4*)(WT2 + k * 128 + c);
  }
  __syncthreads();

  // ================= PHASE 2: conv2 (x from xs2, W2 LDS) =================
#pragma unroll
  for (int i = 0; i < 4; ++i) {
    const float b = Bv2[to4 * 4 + i];
#pragma unroll
    for (int j = 0; j < 4; ++j) acc[i][j] = b;
  }
  for (int ch = 0; ch < 8; ++ch) {
    const int cur = ch & 1, nxt = cur ^ 1;
    float4 ws[2];
    const int k1 = (ch + 1) * 16;
    if (ch < 7) {
#pragma unroll
      for (int j = 0; j < 2; ++j) {
        const int idx = t + j * 256, k = idx >> 5, c = (idx & 31) * 4;
        ws[j] = *(const float4*)(WT2 + (k1 + k) * 128 + c);
      }
    }
    const int k0 = ch * 16;
#pragma unroll
    for (int k = 0; k < 16; ++k) {
      float xv[4], wv[4];
      *(float4*)&xv[0] = *(const float4*)(&xs2[k0 + k][tp * 4]);
      *(float4*)&wv[0] = *(const float4*)(&wpool[cur][k][wcol]);
#pragma unroll
      for (int i = 0; i < 4; ++i)
#pragma unroll
        for (int j = 0; j < 4; ++j)
          acc[i][j] = fmaf(wv[i], xv[j], acc[i][j]);
    }
    if (ch < 7) {
#pragma unroll
      for (int j = 0; j < 2; ++j) {
        const int idx = t + j * 256, k = idx >> 5, c = (idx & 31) * 4;
        *(float4*)(&wpool[nxt][k][c]) = ws[j];
      }
      __syncthreads();   // single barrier per chunk
    }
  }

  // all waves must finish phase-2 reads of xs2/wpool before overwriting
  __syncthreads();

  // epilogue 2: lrelu -> xs2 ; stage W3 as w3s[k][20] across wpool
  float* w3s = &wpool[0][0][0];
#pragma unroll
  for (int i = 0; i < 4; ++i) {
    float v[4];
#pragma unroll
    for (int j = 0; j < 4; ++j) {
      const float x = acc[i][j];
      v[j] = x > 0.f ? x : 0.01f * x;
    }
    *(float4*)(&xs2[to4 * 4 + i][tp * 4]) = *(float4*)v;
  }
  for (int i = t; i < 17 * 128; i += 256)
    w3s[(i & 127) * 20 + (i >> 7)] = W3[i];
  __syncthreads();

  // ===== PHASE 3: conv17 + argmax + mask + hist (8 lanes per pixel) =====
  {
    const int p = t >> 3, s = t & 7;      // pixel 0..31, logit-pair owner
    float s2[2];
    s2[0] = Bv3[2 * s];
    s2[1] = Bv3[2 * s + 1];
    float m = Bv3[16];
#pragma unroll 8
    for (int k = 0; k < 128; ++k) {
      const float xv = xs2[k][p];
      float2 w2 = *(const float2*)&w3s[k * 20 + 2 * s];
      s2[0] = fmaf(xv, w2.x, s2[0]);
      s2[1] = fmaf(xv, w2.y, s2[1]);
      m = fmaf(xv, w3s[k * 20 + 16], m);
    }
    // argmax over 16: local first-max-wins over {2s,2s+1}, then
    // min-index-of-max combine across the 8-lane group
    float bv = s2[0];
    int bi = 2 * s;
    if (s2[1] > bv) { bv = s2[1]; bi = 2 * s + 1; }
#pragma unroll
    for (int d = 1; d < 8; d <<= 1) {
      const float ov = __shfl_xor(bv, d, 64);
      const int oi = __shfl_xor(bi, d, 64);
      if (ov > bv || (ov == bv && oi < bi)) { bv = ov; bi = oi; }
    }
    if (s == 0) {
      inds1[p0 + p] = (unsigned char)bi;
      mask_out[p0 + p] = m > 0.f ? m : 0.01f * m;
      atomicAdd(&lh[bi], 1);
    }
  }
  __syncthreads();
  if (t < 16 && lh[t] > 0) atomicAdd(&cnt1[t], lh[t]);
}

// parallel scan + descriptor emit
template<int NB>
__global__ __launch_bounds__(256) void scan_desc_k(const int* __restrict__ cnt,
    int* __restrict__ off, int* __restrict__ desc, int* __restrict__ ndesc) {
  const int t = threadIdx.x;
  const int lane = t & 63, wvi = t >> 6;
  __shared__ int wsumC[4], wsumD[4];
  const int c = (t < NB) ? cnt[t] : 0;
  const int nb = (c + TPB - 1) / TPB;
  int ic = c, id = nb;
  for (int d = 1; d < 64; d <<= 1) {
    const int uc = __shfl_up(ic, d, 64);
    const int ud = __shfl_up(id, d, 64);
    if (lane >= d) { ic += uc; id += ud; }
  }
  if (lane == 63) { wsumC[wvi] = ic; wsumD[wvi] = id; }
  __syncthreads();
  int bc = 0, bd = 0;
#pragma unroll
  for (int w2 = 0; w2 < 4; ++w2) {
    if (w2 < wvi) { bc += wsumC[w2]; bd += wsumD[w2]; }
  }
  ic += bc; id += bd;
  if (t < NB) {
    off[t] = ic - c;
    const int db = id - nb;
    for (int j = 0; j < nb; ++j) desc[db + j] = (t << 12) | j;
  }
  if (t == NB - 1) *ndesc = id;
}

// two-level scatter
template<typename T>
__global__ __launch_bounds__(256) void scatter_k(const T* __restrict__ bins,
    const int* __restrict__ off, int* __restrict__ cursor,
    int* __restrict__ ord, int nbins) {
  __shared__ int lhist[256], lbase[256], lcur[256];
  const int t = threadIdx.x;
  const int n = blockIdx.x * 256 + t;
  if (t < nbins) { lhist[t] = 0; lcur[t] = 0; }
  __syncthreads();
  const int b = (int)bins[n];
  atomicAdd(&lhist[b], 1);
  __syncthreads();
  if (t < nbins && lhist[t] > 0) lbase[t] = atomicAdd(&cursor[t], lhist[t]);
  __syncthreads();
  const int r = atomicAdd(&lcur[b], 1);
  ord[off[b] + lbase[b] + r] = n;
}

// ---------------------------------------------------------------------------
// chain1 v5 (unchanged): LDS-staged expert weights + x rows; pure-LDS k-loop.
// ---------------------------------------------------------------------------
__global__ __launch_bounds__(256) void chain1_k(const float* __restrict__ xt,
    const int* __restrict__ ord1, const int* __restrict__ off1,
    const int* __restrict__ cnt1, const int* __restrict__ desc1,
    const int* __restrict__ nd1,
    const float* __restrict__ wc21, const float* __restrict__ bc21,
    const float* __restrict__ wc22, const float* __restrict__ bc22,
    const float* __restrict__ wc23, const float* __restrict__ bc23,
    int* __restrict__ e12a, int* __restrict__ cnt2) {
  if ((int)blockIdx.x >= *nd1) return;
  __shared__ float w1s[4096];
  __shared__ float w2s[1024];
  __shared__ float w3s[512];
  __shared__ float bs[80];
  __shared__ float xs_[64][132];
  __shared__ int lh[16];
  const int t = threadIdx.x;
  if (t < 16) lh[t] = 0;
  const int tg = t >> 2, sub = t & 3;
  const int l0 = (t & 63) & ~3;
  const int de = desc1[blockIdx.x];
  const int e = de >> 12, chunk = de & 0xFFF;
  const int cnt = cnt1[e];
  const int pos = chunk * TPB + tg;
  const bool valid = pos < cnt;
  const int n = valid ? ord1[off1[e] + pos] : 0;

  {
    const float4* __restrict__ Wg1 = (const float4*)(wc21 + e * 4096);
#pragma unroll
    for (int j = 0; j < 4; ++j)
      *(float4*)&w1s[t * 4 + j * 1024] = Wg1[t + j * 256];
    const float4* __restrict__ Wg2 = (const float4*)(wc22 + e * 1024);
    *(float4*)&w2s[t * 4] = Wg2[t];
    if (t < 128) {
      const float4* __restrict__ Wg3 = (const float4*)(wc23 + e * 512);
      *(float4*)&w3s[t * 4] = Wg3[t];
    }
    if (t < 32) bs[t] = bc21[e * 32 + t];
    else if (t < 64) bs[t] = bc22[e * 32 + (t - 32)];
    else if (t < 80) bs[t] = bc23[e * 16 + (t - 64)];
  }
  {
    const float4* __restrict__ src = (const float4*)(xt + n * 128 + sub * 32);
    float4 tmp[8];
#pragma unroll
    for (int j = 0; j < 8; ++j) tmp[j] = src[j];
#pragma unroll
    for (int j = 0; j < 8; ++j)
      *(float4*)(&xs_[tg][sub * 32 + 4 * j]) = tmp[j];
  }
  __syncthreads();

  const int wb1 = sub * 8;
  float a[8];
#pragma unroll
  for (int o = 0; o < 8; ++o) a[o] = bs[wb1 + o];
#pragma unroll
  for (int k = 0; k < 128; k += 4) {
    float x4[4];
    *(float4*)x4 = *(const float4*)(&xs_[tg][k]);
#pragma unroll
    for (int kk = 0; kk < 4; ++kk) {
      float w8[8];
      *(float4*)&w8[0] = *(const float4*)&w1s[(k + kk) * 32 + wb1];
      *(float4*)&w8[4] = *(const float4*)&w1s[(k + kk) * 32 + wb1 + 4];
#pragma unroll
      for (int o = 0; o < 8; ++o) a[o] = fmaf(x4[kk], w8[o], a[o]);
    }
  }
#pragma unroll
  for (int o = 0; o < 8; ++o) a[o] = a[o] > 0.f ? a[o] : 0.01f * a[o];

  float b[8];
#pragma unroll
  for (int o = 0; o < 8; ++o) b[o] = bs[32 + wb1 + o];
#pragma unroll
  for (int i = 0; i < 32; ++i) {
    const float hv = __shfl(a[i & 7], l0 + (i >> 3), 64);
    float w8[8];
    *(float4*)&w8[0] = *(const float4*)&w2s[i * 32 + wb1];
    *(float4*)&w8[4] = *(const float4*)&w2s[i * 32 + wb1 + 4];
#pragma unroll
    for (int o = 0; o < 8; ++o) b[o] = fmaf(hv, w8[o], b[o]);
  }
#pragma unroll
  for (int o = 0; o < 8; ++o) b[o] = b[o] > 0.f ? b[o] : 0.01f * b[o];

  float s[4];
#pragma unroll
  for (int j = 0; j < 4; ++j) s[j] = bs[64 + sub * 4 + j];
#pragma unroll
  for (int i = 0; i < 32; ++i) {
    const float hv = __shfl(b[i & 7], l0 + (i >> 3), 64);
    float w4[4];
    *(float4*)w4 = *(const float4*)&w3s[i * 16 + sub * 4];
#pragma unroll
    for (int j = 0; j < 4; ++j) s[j] = fmaf(hv, w4[j], s[j]);
  }

  float bv = s[0];
  int bi = sub * 4;
#pragma unroll
  for (int j = 1; j < 4; ++j) {
    if (s[j] > bv) { bv = s[j]; bi = sub * 4 + j; }
  }
#pragma unroll
  for (int d = 1; d < 4; d <<= 1) {
    const float ov = __shfl_xor(bv, d, 64);
    const int oi = __shfl_xor(bi, d, 64);
    if (ov > bv || (ov == bv && oi < bi)) { bv = ov; bi = oi; }
  }
  const int e12 = e * 16 + bi;
  if (valid && sub == 0) {
    e12a[n] = e12;
    atomicAdd(&lh[bi], 1);
  }
  __syncthreads();
  if (t < 16 && lh[t] > 0)
    atomicAdd(&cnt2[e * 16 + t], lh[t]);
}

// ---------------------------------------------------------------------------
// chain2 v5 (unchanged): LDS-weight-staged. Writes out[n].
// ---------------------------------------------------------------------------
__global__ __launch_bounds__(256) void chain2_k(const float* __restrict__ xt,
    const int* __restrict__ ord2, const int* __restrict__ off2,
    const int* __restrict__ cnt2, const int* __restrict__ desc2,
    const int* __restrict__ nd2,
    const float* __restrict__ wr11, const float* __restrict__ br11,
    const float* __restrict__ wr12, const float* __restrict__ br12,
    const float* __restrict__ wr13, const float* __restrict__ br13,
    float* __restrict__ out) {
  if ((int)blockIdx.x >= *nd2) return;
  __shared__ float w1s[4096];
  __shared__ float w2s[512];
  __shared__ float w3s[16];
  __shared__ float bs[49];
  __shared__ float xs_[64][132];
  const int t = threadIdx.x;
  const int tg = t >> 2, sub = t & 3;
  const int l0 = (t & 63) & ~3;
  const int de = desc2[blockIdx.x];
  const int e12 = de >> 12, chunk = de & 0xFFF;
  const int cnt = cnt2[e12];
  const int pos = chunk * TPB + tg;
  const bool valid = pos < cnt;
  const int n = valid ? ord2[off2[e12] + pos] : 0;

  {
    const float4* __restrict__ Wg1 = (const float4*)(wr11 + e12 * 4096);
#pragma unroll
    for (int j = 0; j < 4; ++j)
      *(float4*)&w1s[t * 4 + j * 1024] = Wg1[t + j * 256];
    if (t < 128) {
      const float4* __restrict__ Wg2 = (const float4*)(wr12 + e12 * 512);
      *(float4*)&w2s[t * 4] = Wg2[t];
    }
    if (t < 16) w3s[t] = wr13[e12 * 16 + t];
    if (t < 32) bs[t] = br11[e12 * 32 + t];
    else if (t < 48) bs[t] = br12[e12 * 16 + (t - 32)];
    else if (t == 48) bs[48] = br13[e12];
  }
  {
    const float4* __restrict__ src = (const float4*)(xt + n * 128 + sub * 32);
    float4 tmp[8];
#pragma unroll
    for (int j = 0; j < 8; ++j) tmp[j] = src[j];
#pragma unroll
    for (int j = 0; j < 8; ++j)
      *(float4*)(&xs_[tg][sub * 32 + 4 * j]) = tmp[j];
  }
  __syncthreads();

  const int wb1 = sub * 8;
  float a[8];
#pragma unroll
  for (int o = 0; o < 8; ++o) a[o] = bs[wb1 + o];
#pragma unroll
  for (int k = 0; k < 128; k += 4) {
    float x4[4];
    *(float4*)x4 = *(const float4*)(&xs_[tg][k]);
#pragma unroll
    for (int kk = 0; kk < 4; ++kk) {
      float w8[8];
      *(float4*)&w8[0] = *(const float4*)&w1s[(k + kk) * 32 + wb1];
      *(float4*)&w8[4] = *(const float4*)&w1s[(k + kk) * 32 + wb1 + 4];
#pragma unroll
      for (int o = 0; o < 8; ++o) a[o] = fmaf(x4[kk], w8[o], a[o]);
    }
  }
#pragma unroll
  for (int o = 0; o < 8; ++o) a[o] = a[o] > 0.f ? a[o] : 0.01f * a[o];

  float s[4];
#pragma unroll
  for (int j = 0; j < 4; ++j) s[j] = bs[32 + sub * 4 + j];
#pragma unroll
  for (int i = 0; i < 32; ++i) {
    const float hv = __shfl(a[i & 7], l0 + (i >> 3), 64);
    float w4[4];
    *(float4*)w4 = *(const float4*)&w2s[i * 16 + sub * 4];
#pragma unroll
    for (int j = 0; j < 4; ++j) s[j] = fmaf(hv, w4[j], s[j]);
  }
#pragma unroll
  for (int j = 0; j < 4; ++j) s[j] = s[j] > 0.f ? s[j] : 0.01f * s[j];

  float r = bs[48];
#pragma unroll
  for (int i = 0; i < 16; ++i) {
    const float hv = __shfl(s[i & 3], l0 + (i >> 2), 64);
    r = fmaf(hv, w3s[i], r);
  }

  if (valid && sub == 0) out[n] = ((float)e12 + r) * (1.0f / 256.0f);
}

// ---------------------------------------------------------------------------
extern "C" void kernel_launch(void* const* d_in, const int* in_sizes, int n_in,
                              void* d_out, int out_size, void* d_ws,
                              size_t ws_size, hipStream_t stream) {
  const float* x_in  = (const float*)d_in[0];
  const float* w_c11 = (const float*)d_in[1];
  const float* b_c11 = (const float*)d_in[2];
  const float* w_c12 = (const float*)d_in[3];
  const float* b_c12 = (const float*)d_in[4];
  const float* w_c13 = (const float*)d_in[5];
  const float* b_c13 = (const float*)d_in[6];
  const float* w_c21 = (const float*)d_in[7];
  const float* b_c21 = (const float*)d_in[8];
  const float* w_c22 = (const float*)d_in[9];
  const float* b_c22 = (const float*)d_in[10];
  const float* w_c23 = (const float*)d_in[11];
  const float* b_c23 = (const float*)d_in[12];
  const float* w_r11 = (const float*)d_in[13];
  const float* b_r11 = (const float*)d_in[14];
  const float* w_r12 = (const float*)d_in[15];
  const float* b_r12 = (const float*)d_in[16];
  const float* w_r13 = (const float*)d_in[17];
  const float* b_r13 = (const float*)d_in[18];

  float* out = (float*)d_out;   // [0..N): x_real (token order), [N..2N): mask

  float* R0 = (float*)d_ws;
  float* R1 = R0 + 128 * NPIX;
  float* R2 = R1 + 128 * NPIX;

  float* xt = R0;
  unsigned char* inds1 = (unsigned char*)R2;   // N bytes
  float* wT1 = R2 + 12288;
  float* wT2 = wT1 + 16384;
  int* S = (int*)R2 + 45056;

  int* cnt1  = S;            // 16
  int* cur1  = S + 16;       // 16
  int* off1  = S + 32;       // 16
  int* nd1   = S + 48;       // 1 (+pad)
  int* desc1 = S + 64;       // 1024
  int* cnt2  = S + 1088;     // 256
  int* cur2  = S + 1344;     // 256
  int* off2  = S + 1600;     // 256
  int* nd2   = S + 1856;     // 1 (+pad)
  int* desc2 = S + 1872;     // 1024

  int* ib   = (int*)R1;
  int* ord1 = ib;            // N
  int* ord2 = ib + NPIX;     // N
  int* e12a = ib + 2 * NPIX; // N

  wtrans2_k<<<32, 256, 0, stream>>>(w_c11, wT1, w_c12, wT2, S);
  convfused_k<<<NPIX / 32, 256, 0, stream>>>(x_in, wT1, b_c11, wT2, b_c12,
      w_c13, b_c13, inds1, out + NPIX, cnt1, xt);
  scan_desc_k<16><<<1, 256, 0, stream>>>(cnt1, off1, desc1, nd1);
  scatter_k<unsigned char><<<NPIX / 256, 256, 0, stream>>>(inds1, off1, cur1,
                                                           ord1, 16);
  chain1_k<<<NPIX / TPB + 16, 256, 0, stream>>>(xt, ord1, off1, cnt1, desc1,
      nd1, w_c21, b_c21, w_c22, b_c22, w_c23, b_c23, e12a, cnt2);
  scan_desc_k<256><<<1, 256, 0, stream>>>(cnt2, off2, desc2, nd2);
  scatter_k<int><<<NPIX / 256, 256, 0, stream>>>(e12a, off2, cur2, ord2, 256);
  chain2_k<<<NPIX / TPB + 256, 256, 0, stream>>>(xt, ord2, off2, cnt2, desc2,
      nd2, w_r11, b_r11, w_r12, b_r12, w_r13, b_r13, out);
}

// Round 12
// 123.066 us; speedup vs baseline: 2.0415x; 1.2999x over previous
//
#include <hip/hip_runtime.h>

#define NPIX 49152   // B*H*W = 1*192*256
#define H_ 192
#define W_ 256
#define TPB 64       // tokens per chain block (64 tokens x 4 lanes = 256 thr)

// ---------------------------------------------------------------------------
// both weight transposes (32 blocks) + zero binning counters (block 0)
// ---------------------------------------------------------------------------
__global__ __launch_bounds__(256) void wtrans2_k(const float* __restrict__ Wa,
    float* __restrict__ WTa, const float* __restrict__ Wb,
    float* __restrict__ WTb, int* __restrict__ S) {
  const int b = blockIdx.x;
  const float* __restrict__ W = (b < 16) ? Wa : Wb;
  float* __restrict__ WT = (b < 16) ? WTa : WTb;
  const int bb = b & 15;
  __shared__ float tile[32][33];
  const int bx = bb & 3, by = bb >> 2;
  const int c = threadIdx.x & 31, r0 = threadIdx.x >> 5;
#pragma unroll
  for (int j = 0; j < 4; ++j) {
    const int r = r0 + j * 8;
    tile[r][c] = W[(by * 32 + r) * 128 + bx * 32 + c];
  }
  __syncthreads();
#pragma unroll
  for (int j = 0; j < 4; ++j) {
    const int r = r0 + j * 8;
    WT[(bx * 32 + r) * 128 + by * 32 + c] = tile[c][r];
  }
  if (b == 0) {
    const int t = threadIdx.x;
    if (t < 32) S[t] = 0;        // cnt1 + cur1
    S[1088 + t] = 0;             // cnt2
    S[1344 + t] = 0;             // cur2
  }
}

// ---------------------------------------------------------------------------
// FUSED conv1 + conv2 + conv17 + argmax + mask + histogram + x transpose.
// Wave-uniform weight addressing: each wave owns 16 output channels x 64
// pixels (lane = pixel). Weights ride the SCALAR path (s_load + v_fma v,s,v)
// -> zero LDS/VALU cost for weights; x is coalesced global (ph1, L2-dedup'd
// across the 8 waves) or conflict-free ds_read_b32 (ph2). 4 barriers total.
// Per-output FMA chains (bias then k ascending) bitwise identical to before.
// ---------------------------------------------------------------------------
__global__ __launch_bounds__(512) void convfused_k(const float* __restrict__ X,
    const float* __restrict__ WT1, const float* __restrict__ Bv1,
    const float* __restrict__ WT2, const float* __restrict__ Bv2,
    const float* __restrict__ W3, const float* __restrict__ Bv3,
    unsigned char* __restrict__ inds1, float* __restrict__ mask_out,
    int* __restrict__ cnt1, float* __restrict__ xt) {
  __shared__ float xs2[128][64];   // 32 KB inter-phase activations
  __shared__ float w3s[128 * 20];  // 10 KB W3 [k][20]
  __shared__ int lh[16];
  const int t = threadIdx.x;
  const int px = t & 63;           // lane = pixel within tile
  const int p0 = blockIdx.x * 64;
  int ob = (t >> 6) * 16;          // wave's 16-output base (wave-uniform)
  ob = __builtin_amdgcn_readfirstlane(ob);
  if (t < 16) lh[t] = 0;

  const int pglob = p0 + px;
  float* __restrict__ xtp = xt + ((pglob & 255) * H_ + (pglob >> 8)) * 128;

  float acc[16];

  // ================= PHASE 1: conv1 (x global dwords, W scalar) ==========
  const float* __restrict__ W1u = WT1 + ob;   // uniform base
#pragma unroll
  for (int o = 0; o < 16; ++o) acc[o] = Bv1[ob + o];

  float xc[16], xn[16];
#pragma unroll
  for (int kk = 0; kk < 16; ++kk) xc[kk] = X[kk * NPIX + pglob];

  for (int ch = 0; ch < 8; ++ch) {
    const int k0 = ch * 16;
    if (ch < 7) {
#pragma unroll
      for (int kk = 0; kk < 16; ++kk)
        xn[kk] = X[(k0 + 16 + kk) * NPIX + pglob];
    }
    // transpose side-channel: wave 0 already holds x[k0..k0+16) per pixel
    if (t < 64) {
#pragma unroll
      for (int q = 0; q < 4; ++q) {
        float4 v;
        v.x = xc[4 * q]; v.y = xc[4 * q + 1];
        v.z = xc[4 * q + 2]; v.w = xc[4 * q + 3];
        *(float4*)(xtp + k0 + 4 * q) = v;
      }
    }
#pragma unroll
    for (int kk = 0; kk < 16; ++kk) {
      const float xv = xc[kk];
#pragma unroll
      for (int o = 0; o < 16; ++o)
        acc[o] = fmaf(xv, W1u[(k0 + kk) * 128 + o], acc[o]);
    }
    if (ch < 7) {
#pragma unroll
      for (int kk = 0; kk < 16; ++kk) xc[kk] = xn[kk];
    }
  }
#pragma unroll
  for (int o = 0; o < 16; ++o) {
    const float v = acc[o];
    xs2[ob + o][px] = v > 0.f ? v : 0.01f * v;
  }
  __syncthreads();

  // ================= PHASE 2: conv2 (x from LDS b32, W scalar) ===========
  const float* __restrict__ W2u = WT2 + ob;
#pragma unroll
  for (int o = 0; o < 16; ++o) acc[o] = Bv2[ob + o];
#pragma unroll 8
  for (int k = 0; k < 128; ++k) {
    const float xv = xs2[k][px];
#pragma unroll
    for (int o = 0; o < 16; ++o)
      acc[o] = fmaf(xv, W2u[k * 128 + o], acc[o]);
  }
  __syncthreads();   // all phase-2 reads of xs2 complete

  // epilogue 2: lrelu -> xs2 ; stage W3 as w3s[k][20]
#pragma unroll
  for (int o = 0; o < 16; ++o) {
    const float v = acc[o];
    xs2[ob + o][px] = v > 0.f ? v : 0.01f * v;
  }
  for (int i = t; i < 17 * 128; i += 512)
    w3s[(i & 127) * 20 + (i >> 7)] = W3[i];
  __syncthreads();

  // ===== PHASE 3: conv17 + argmax + mask + hist (8 lanes per pixel) =====
  {
    const int p = t >> 3, s = t & 7;      // pixel 0..63, logit-pair owner
    float s2[2];
    s2[0] = Bv3[2 * s];
    s2[1] = Bv3[2 * s + 1];
    float m = Bv3[16];
#pragma unroll 8
    for (int k = 0; k < 128; ++k) {
      const float xv = xs2[k][p];
      float2 w2 = *(const float2*)&w3s[k * 20 + 2 * s];
      s2[0] = fmaf(xv, w2.x, s2[0]);
      s2[1] = fmaf(xv, w2.y, s2[1]);
      m = fmaf(xv, w3s[k * 20 + 16], m);
    }
    // argmax over 16: local first-max-wins over {2s,2s+1}, then
    // min-index-of-max combine across the 8-lane group
    float bv = s2[0];
    int bi = 2 * s;
    if (s2[1] > bv) { bv = s2[1]; bi = 2 * s + 1; }
#pragma unroll
    for (int d = 1; d < 8; d <<= 1) {
      const float ov = __shfl_xor(bv, d, 64);
      const int oi = __shfl_xor(bi, d, 64);
      if (ov > bv || (ov == bv && oi < bi)) { bv = ov; bi = oi; }
    }
    if (s == 0) {
      inds1[p0 + p] = (unsigned char)bi;
      mask_out[p0 + p] = m > 0.f ? m : 0.01f * m;
      atomicAdd(&lh[bi], 1);
    }
  }
  __syncthreads();
  if (t < 16 && lh[t] > 0) atomicAdd(&cnt1[t], lh[t]);
}

// parallel scan + descriptor emit
template<int NB>
__global__ __launch_bounds__(256) void scan_desc_k(const int* __restrict__ cnt,
    int* __restrict__ off, int* __restrict__ desc, int* __restrict__ ndesc) {
  const int t = threadIdx.x;
  const int lane = t & 63, wvi = t >> 6;
  __shared__ int wsumC[4], wsumD[4];
  const int c = (t < NB) ? cnt[t] : 0;
  const int nb = (c + TPB - 1) / TPB;
  int ic = c, id = nb;
  for (int d = 1; d < 64; d <<= 1) {
    const int uc = __shfl_up(ic, d, 64);
    const int ud = __shfl_up(id, d, 64);
    if (lane >= d) { ic += uc; id += ud; }
  }
  if (lane == 63) { wsumC[wvi] = ic; wsumD[wvi] = id; }
  __syncthreads();
  int bc = 0, bd = 0;
#pragma unroll
  for (int w2 = 0; w2 < 4; ++w2) {
    if (w2 < wvi) { bc += wsumC[w2]; bd += wsumD[w2]; }
  }
  ic += bc; id += bd;
  if (t < NB) {
    off[t] = ic - c;
    const int db = id - nb;
    for (int j = 0; j < nb; ++j) desc[db + j] = (t << 12) | j;
  }
  if (t == NB - 1) *ndesc = id;
}

// two-level scatter
template<typename T>
__global__ __launch_bounds__(256) void scatter_k(const T* __restrict__ bins,
    const int* __restrict__ off, int* __restrict__ cursor,
    int* __restrict__ ord, int nbins) {
  __shared__ int lhist[256], lbase[256], lcur[256];
  const int t = threadIdx.x;
  const int n = blockIdx.x * 256 + t;
  if (t < nbins) { lhist[t] = 0; lcur[t] = 0; }
  __syncthreads();
  const int b = (int)bins[n];
  atomicAdd(&lhist[b], 1);
  __syncthreads();
  if (t < nbins && lhist[t] > 0) lbase[t] = atomicAdd(&cursor[t], lhist[t]);
  __syncthreads();
  const int r = atomicAdd(&lcur[b], 1);
  ord[off[b] + lbase[b] + r] = n;
}

// ---------------------------------------------------------------------------
// chain1 v5 (unchanged): LDS-staged expert weights + x rows; pure-LDS k-loop.
// ---------------------------------------------------------------------------
__global__ __launch_bounds__(256) void chain1_k(const float* __restrict__ xt,
    const int* __restrict__ ord1, const int* __restrict__ off1,
    const int* __restrict__ cnt1, const int* __restrict__ desc1,
    const int* __restrict__ nd1,
    const float* __restrict__ wc21, const float* __restrict__ bc21,
    const float* __restrict__ wc22, const float* __restrict__ bc22,
    const float* __restrict__ wc23, const float* __restrict__ bc23,
    int* __restrict__ e12a, int* __restrict__ cnt2) {
  if ((int)blockIdx.x >= *nd1) return;
  __shared__ float w1s[4096];
  __shared__ float w2s[1024];
  __shared__ float w3s[512];
  __shared__ float bs[80];
  __shared__ float xs_[64][132];
  __shared__ int lh[16];
  const int t = threadIdx.x;
  if (t < 16) lh[t] = 0;
  const int tg = t >> 2, sub = t & 3;
  const int l0 = (t & 63) & ~3;
  const int de = desc1[blockIdx.x];
  const int e = de >> 12, chunk = de & 0xFFF;
  const int cnt = cnt1[e];
  const int pos = chunk * TPB + tg;
  const bool valid = pos < cnt;
  const int n = valid ? ord1[off1[e] + pos] : 0;

  {
    const float4* __restrict__ Wg1 = (const float4*)(wc21 + e * 4096);
#pragma unroll
    for (int j = 0; j < 4; ++j)
      *(float4*)&w1s[t * 4 + j * 1024] = Wg1[t + j * 256];
    const float4* __restrict__ Wg2 = (const float4*)(wc22 + e * 1024);
    *(float4*)&w2s[t * 4] = Wg2[t];
    if (t < 128) {
      const float4* __restrict__ Wg3 = (const float4*)(wc23 + e * 512);
      *(float4*)&w3s[t * 4] = Wg3[t];
    }
    if (t < 32) bs[t] = bc21[e * 32 + t];
    else if (t < 64) bs[t] = bc22[e * 32 + (t - 32)];
    else if (t < 80) bs[t] = bc23[e * 16 + (t - 64)];
  }
  {
    const float4* __restrict__ src = (const float4*)(xt + n * 128 + sub * 32);
    float4 tmp[8];
#pragma unroll
    for (int j = 0; j < 8; ++j) tmp[j] = src[j];
#pragma unroll
    for (int j = 0; j < 8; ++j)
      *(float4*)(&xs_[tg][sub * 32 + 4 * j]) = tmp[j];
  }
  __syncthreads();

  const int wb1 = sub * 8;
  float a[8];
#pragma unroll
  for (int o = 0; o < 8; ++o) a[o] = bs[wb1 + o];
#pragma unroll
  for (int k = 0; k < 128; k += 4) {
    float x4[4];
    *(float4*)x4 = *(const float4*)(&xs_[tg][k]);
#pragma unroll
    for (int kk = 0; kk < 4; ++kk) {
      float w8[8];
      *(float4*)&w8[0] = *(const float4*)&w1s[(k + kk) * 32 + wb1];
      *(float4*)&w8[4] = *(const float4*)&w1s[(k + kk) * 32 + wb1 + 4];
#pragma unroll
      for (int o = 0; o < 8; ++o) a[o] = fmaf(x4[kk], w8[o], a[o]);
    }
  }
#pragma unroll
  for (int o = 0; o < 8; ++o) a[o] = a[o] > 0.f ? a[o] : 0.01f * a[o];

  float b[8];
#pragma unroll
  for (int o = 0; o < 8; ++o) b[o] = bs[32 + wb1 + o];
#pragma unroll
  for (int i = 0; i < 32; ++i) {
    const float hv = __shfl(a[i & 7], l0 + (i >> 3), 64);
    float w8[8];
    *(float4*)&w8[0] = *(const float4*)&w2s[i * 32 + wb1];
    *(float4*)&w8[4] = *(const float4*)&w2s[i * 32 + wb1 + 4];
#pragma unroll
    for (int o = 0; o < 8; ++o) b[o] = fmaf(hv, w8[o], b[o]);
  }
#pragma unroll
  for (int o = 0; o < 8; ++o) b[o] = b[o] > 0.f ? b[o] : 0.01f * b[o];

  float s[4];
#pragma unroll
  for (int j = 0; j < 4; ++j) s[j] = bs[64 + sub * 4 + j];
#pragma unroll
  for (int i = 0; i < 32; ++i) {
    const float hv = __shfl(b[i & 7], l0 + (i >> 3), 64);
    float w4[4];
    *(float4*)w4 = *(const float4*)&w3s[i * 16 + sub * 4];
#pragma unroll
    for (int j = 0; j < 4; ++j) s[j] = fmaf(hv, w4[j], s[j]);
  }

  float bv = s[0];
  int bi = sub * 4;
#pragma unroll
  for (int j = 1; j < 4; ++j) {
    if (s[j] > bv) { bv = s[j]; bi = sub * 4 + j; }
  }
#pragma unroll
  for (int d = 1; d < 4; d <<= 1) {
    const float ov = __shfl_xor(bv, d, 64);
    const int oi = __shfl_xor(bi, d, 64);
    if (ov > bv || (ov == bv && oi < bi)) { bv = ov; bi = oi; }
  }
  const int e12 = e * 16 + bi;
  if (valid && sub == 0) {
    e12a[n] = e12;
    atomicAdd(&lh[bi], 1);
  }
  __syncthreads();
  if (t < 16 && lh[t] > 0)
    atomicAdd(&cnt2[e * 16 + t], lh[t]);
}

// ---------------------------------------------------------------------------
// chain2 v5 (unchanged): LDS-weight-staged. Writes out[n].
// ---------------------------------------------------------------------------
__global__ __launch_bounds__(256) void chain2_k(const float* __restrict__ xt,
    const int* __restrict__ ord2, const int* __restrict__ off2,
    const int* __restrict__ cnt2, const int* __restrict__ desc2,
    const int* __restrict__ nd2,
    const float* __restrict__ wr11, const float* __restrict__ br11,
    const float* __restrict__ wr12, const float* __restrict__ br12,
    const float* __restrict__ wr13, const float* __restrict__ br13,
    float* __restrict__ out) {
  if ((int)blockIdx.x >= *nd2) return;
  __shared__ float w1s[4096];
  __shared__ float w2s[512];
  __shared__ float w3s[16];
  __shared__ float bs[49];
  __shared__ float xs_[64][132];
  const int t = threadIdx.x;
  const int tg = t >> 2, sub = t & 3;
  const int l0 = (t & 63) & ~3;
  const int de = desc2[blockIdx.x];
  const int e12 = de >> 12, chunk = de & 0xFFF;
  const int cnt = cnt2[e12];
  const int pos = chunk * TPB + tg;
  const bool valid = pos < cnt;
  const int n = valid ? ord2[off2[e12] + pos] : 0;

  {
    const float4* __restrict__ Wg1 = (const float4*)(wr11 + e12 * 4096);
#pragma unroll
    for (int j = 0; j < 4; ++j)
      *(float4*)&w1s[t * 4 + j * 1024] = Wg1[t + j * 256];
    if (t < 128) {
      const float4* __restrict__ Wg2 = (const float4*)(wr12 + e12 * 512);
      *(float4*)&w2s[t * 4] = Wg2[t];
    }
    if (t < 16) w3s[t] = wr13[e12 * 16 + t];
    if (t < 32) bs[t] = br11[e12 * 32 + t];
    else if (t < 48) bs[t] = br12[e12 * 16 + (t - 32)];
    else if (t == 48) bs[48] = br13[e12];
  }
  {
    const float4* __restrict__ src = (const float4*)(xt + n * 128 + sub * 32);
    float4 tmp[8];
#pragma unroll
    for (int j = 0; j < 8; ++j) tmp[j] = src[j];
#pragma unroll
    for (int j = 0; j < 8; ++j)
      *(float4*)(&xs_[tg][sub * 32 + 4 * j]) = tmp[j];
  }
  __syncthreads();

  const int wb1 = sub * 8;
  float a[8];
#pragma unroll
  for (int o = 0; o < 8; ++o) a[o] = bs[wb1 + o];
#pragma unroll
  for (int k = 0; k < 128; k += 4) {
    float x4[4];
    *(float4*)x4 = *(const float4*)(&xs_[tg][k]);
#pragma unroll
    for (int kk = 0; kk < 4; ++kk) {
      float w8[8];
      *(float4*)&w8[0] = *(const float4*)&w1s[(k + kk) * 32 + wb1];
      *(float4*)&w8[4] = *(const float4*)&w1s[(k + kk) * 32 + wb1 + 4];
#pragma unroll
      for (int o = 0; o < 8; ++o) a[o] = fmaf(x4[kk], w8[o], a[o]);
    }
  }
#pragma unroll
  for (int o = 0; o < 8; ++o) a[o] = a[o] > 0.f ? a[o] : 0.01f * a[o];

  float s[4];
#pragma unroll
  for (int j = 0; j < 4; ++j) s[j] = bs[32 + sub * 4 + j];
#pragma unroll
  for (int i = 0; i < 32; ++i) {
    const float hv = __shfl(a[i & 7], l0 + (i >> 3), 64);
    float w4[4];
    *(float4*)w4 = *(const float4*)&w2s[i * 16 + sub * 4];
#pragma unroll
    for (int j = 0; j < 4; ++j) s[j] = fmaf(hv, w4[j], s[j]);
  }
#pragma unroll
  for (int j = 0; j < 4; ++j) s[j] = s[j] > 0.f ? s[j] : 0.01f * s[j];

  float r = bs[48];
#pragma unroll
  for (int i = 0; i < 16; ++i) {
    const float hv = __shfl(s[i & 3], l0 + (i >> 2), 64);
    r = fmaf(hv, w3s[i], r);
  }

  if (valid && sub == 0) out[n] = ((float)e12 + r) * (1.0f / 256.0f);
}

// ---------------------------------------------------------------------------
extern "C" void kernel_launch(void* const* d_in, const int* in_sizes, int n_in,
                              void* d_out, int out_size, void* d_ws,
                              size_t ws_size, hipStream_t stream) {
  const float* x_in  = (const float*)d_in[0];
  const float* w_c11 = (const float*)d_in[1];
  const float* b_c11 = (const float*)d_in[2];
  const float* w_c12 = (const float*)d_in[3];
  const float* b_c12 = (const float*)d_in[4];
  const float* w_c13 = (const float*)d_in[5];
  const float* b_c13 = (const float*)d_in[6];
  const float* w_c21 = (const float*)d_in[7];
  const float* b_c21 = (const float*)d_in[8];
  const float* w_c22 = (const float*)d_in[9];
  const float* b_c22 = (const float*)d_in[10];
  const float* w_c23 = (const float*)d_in[11];
  const float* b_c23 = (const float*)d_in[12];
  const float* w_r11 = (const float*)d_in[13];
  const float* b_r11 = (const float*)d_in[14];
  const float* w_r12 = (const float*)d_in[15];
  const float* b_r12 = (const float*)d_in[16];
  const float* w_r13 = (const float*)d_in[17];
  const float* b_r13 = (const float*)d_in[18];

  float* out = (float*)d_out;   // [0..N): x_real (token order), [N..2N): mask

  float* R0 = (float*)d_ws;
  float* R1 = R0 + 128 * NPIX;
  float* R2 = R1 + 128 * NPIX;

  float* xt = R0;
  unsigned char* inds1 = (unsigned char*)R2;   // N bytes
  float* wT1 = R2 + 12288;
  float* wT2 = wT1 + 16384;
  int* S = (int*)R2 + 45056;

  int* cnt1  = S;            // 16
  int* cur1  = S + 16;       // 16
  int* off1  = S + 32;       // 16
  int* nd1   = S + 48;       // 1 (+pad)
  int* desc1 = S + 64;       // 1024
  int* cnt2  = S + 1088;     // 256
  int* cur2  = S + 1344;     // 256
  int* off2  = S + 1600;     // 256
  int* nd2   = S + 1856;     // 1 (+pad)
  int* desc2 = S + 1872;     // 1024

  int* ib   = (int*)R1;
  int* ord1 = ib;            // N
  int* ord2 = ib + NPIX;     // N
  int* e12a = ib + 2 * NPIX; // N

  wtrans2_k<<<32, 256, 0, stream>>>(w_c11, wT1, w_c12, wT2, S);
  convfused_k<<<NPIX / 64, 512, 0, stream>>>(x_in, wT1, b_c11, wT2, b_c12,
      w_c13, b_c13, inds1, out + NPIX, cnt1, xt);
  scan_desc_k<16><<<1, 256, 0, stream>>>(cnt1, off1, desc1, nd1);
  scatter_k<unsigned char><<<NPIX / 256, 256, 0, stream>>>(inds1, off1, cur1,
                                                           ord1, 16);
  chain1_k<<<NPIX / TPB + 16, 256, 0, stream>>>(xt, ord1, off1, cnt1, desc1,
      nd1, w_c21, b_c21, w_c22, b_c22, w_c23, b_c23, e12a, cnt2);
  scan_desc_k<256><<<1, 256, 0, stream>>>(cnt2, off2, desc2, nd2);
  scatter_k<int><<<NPIX / 256, 256, 0, stream>>>(e12a, off2, cur2, ord2, 256);
  chain2_k<<<NPIX / TPB + 256, 256, 0, stream>>>(xt, ord2, off2, cnt2, desc2,
      nd2, w_r11, b_r11, w_r12, b_r12, w_r13, b_r13, out);
}

// Round 13
// 122.994 us; speedup vs baseline: 2.0427x; 1.0006x over previous
//
#include <hip/hip_runtime.h>

#define NPIX 49152   // B*H*W = 1*192*256
#define H_ 192
#define W_ 256
#define TPB 64       // tokens per chain block (64 tokens x 4 lanes = 256 thr)

// ---------------------------------------------------------------------------
// both weight transposes (32 blocks) + zero binning counters (block 0)
// ---------------------------------------------------------------------------
__global__ __launch_bounds__(256) void wtrans2_k(const float* __restrict__ Wa,
    float* __restrict__ WTa, const float* __restrict__ Wb,
    float* __restrict__ WTb, int* __restrict__ S) {
  const int b = blockIdx.x;
  const float* __restrict__ W = (b < 16) ? Wa : Wb;
  float* __restrict__ WT = (b < 16) ? WTa : WTb;
  const int bb = b & 15;
  __shared__ float tile[32][33];
  const int bx = bb & 3, by = bb >> 2;
  const int c = threadIdx.x & 31, r0 = threadIdx.x >> 5;
#pragma unroll
  for (int j = 0; j < 4; ++j) {
    const int r = r0 + j * 8;
    tile[r][c] = W[(by * 32 + r) * 128 + bx * 32 + c];
  }
  __syncthreads();
#pragma unroll
  for (int j = 0; j < 4; ++j) {
    const int r = r0 + j * 8;
    WT[(bx * 32 + r) * 128 + by * 32 + c] = tile[c][r];
  }
  if (b == 0) {
    const int t = threadIdx.x;
    if (t < 32) S[t] = 0;        // cnt1 + cur1
    S[1088 + t] = 0;             // cnt2
    S[1344 + t] = 0;             // cur2
  }
}

// ---------------------------------------------------------------------------
// FUSED conv1 + conv2 + conv17 + argmax + mask + histogram + x transpose.
// x staged ONCE into LDS (wave w loads its 16 k-rows); both conv phases read
// x via conflict-free ds_read_b32; weights ride the scalar path (wave-uniform
// base + s_load). xt transpose done from LDS with fully-coalesced 512-B row
// bursts. Per-output FMA chains (bias then k ascending) bitwise identical.
// ---------------------------------------------------------------------------
__global__ __launch_bounds__(512) void convfused_k(const float* __restrict__ X,
    const float* __restrict__ WT1, const float* __restrict__ Bv1,
    const float* __restrict__ WT2, const float* __restrict__ Bv2,
    const float* __restrict__ W3, const float* __restrict__ Bv3,
    unsigned char* __restrict__ inds1, float* __restrict__ mask_out,
    int* __restrict__ cnt1, float* __restrict__ xt) {
  __shared__ float xs2[128][65];   // 33.3 KB raw x, then activations (pad 65)
  __shared__ float w3s[128 * 20];  // 10 KB W3 [k][20]
  __shared__ int lh[16];
  const int t = threadIdx.x;
  const int px = t & 63;           // lane = pixel within tile
  const int p0 = blockIdx.x * 64;
  int ob = (t >> 6) * 16;          // wave's 16-output base == its k-row base
  ob = __builtin_amdgcn_readfirstlane(ob);
  if (t < 16) lh[t] = 0;

  // ---- stage raw x: wave w loads k rows [ob, ob+16) for all 64 px ----
  {
    float xr[16];
#pragma unroll
    for (int kk = 0; kk < 16; ++kk)
      xr[kk] = X[(ob + kk) * NPIX + p0 + px];
#pragma unroll
    for (int kk = 0; kk < 16; ++kk)
      xs2[ob + kk][px] = xr[kk];
  }
  __syncthreads();

  float acc[16];

  // ================= PHASE 1: conv1 (x from LDS, W scalar) ===============
  const float* __restrict__ W1u = WT1 + ob;   // uniform base
#pragma unroll
  for (int o = 0; o < 16; ++o) acc[o] = Bv1[ob + o];
#pragma unroll 8
  for (int k = 0; k < 128; ++k) {
    const float xv = xs2[k][px];
#pragma unroll
    for (int o = 0; o < 16; ++o)
      acc[o] = fmaf(xv, W1u[k * 128 + o], acc[o]);
  }

  // ---- xt transpose write (coalesced 512-B row bursts from LDS cols) ----
#pragma unroll
  for (int i = 0; i < 4; ++i) {
    const int idx = t * 4 + i;
    const int tok = idx >> 5, c4 = idx & 31;   // token 0..63, f4-col 0..31
    const int pg = p0 + tok;
    float4 v;
    v.x = xs2[c4 * 4 + 0][tok];
    v.y = xs2[c4 * 4 + 1][tok];
    v.z = xs2[c4 * 4 + 2][tok];
    v.w = xs2[c4 * 4 + 3][tok];
    *(float4*)(xt + ((pg & 255) * H_ + (pg >> 8)) * 128 + c4 * 4) = v;
  }
  __syncthreads();   // xt LDS reads + phase-1 reads done before overwrite

  // epilogue 1: lrelu -> xs2 (activations)
#pragma unroll
  for (int o = 0; o < 16; ++o) {
    const float v = acc[o];
    xs2[ob + o][px] = v > 0.f ? v : 0.01f * v;
  }
  __syncthreads();

  // ================= PHASE 2: conv2 (x from LDS, W scalar) ===============
  const float* __restrict__ W2u = WT2 + ob;
#pragma unroll
  for (int o = 0; o < 16; ++o) acc[o] = Bv2[ob + o];
#pragma unroll 8
  for (int k = 0; k < 128; ++k) {
    const float xv = xs2[k][px];
#pragma unroll
    for (int o = 0; o < 16; ++o)
      acc[o] = fmaf(xv, W2u[k * 128 + o], acc[o]);
  }
  __syncthreads();   // all phase-2 reads of xs2 complete

  // epilogue 2: lrelu -> xs2 ; stage W3 as w3s[k][20]
#pragma unroll
  for (int o = 0; o < 16; ++o) {
    const float v = acc[o];
    xs2[ob + o][px] = v > 0.f ? v : 0.01f * v;
  }
  for (int i = t; i < 17 * 128; i += 512)
    w3s[(i & 127) * 20 + (i >> 7)] = W3[i];
  __syncthreads();

  // ===== PHASE 3: conv17 + argmax + mask + hist (8 lanes per pixel) =====
  {
    const int p = t >> 3, s = t & 7;      // pixel 0..63, logit-pair owner
    float s2[2];
    s2[0] = Bv3[2 * s];
    s2[1] = Bv3[2 * s + 1];
    float m = Bv3[16];
#pragma unroll 8
    for (int k = 0; k < 128; ++k) {
      const float xv = xs2[k][p];
      float2 w2 = *(const float2*)&w3s[k * 20 + 2 * s];
      s2[0] = fmaf(xv, w2.x, s2[0]);
      s2[1] = fmaf(xv, w2.y, s2[1]);
      m = fmaf(xv, w3s[k * 20 + 16], m);
    }
    // argmax over 16: local first-max-wins over {2s,2s+1}, then
    // min-index-of-max combine across the 8-lane group
    float bv = s2[0];
    int bi = 2 * s;
    if (s2[1] > bv) { bv = s2[1]; bi = 2 * s + 1; }
#pragma unroll
    for (int d = 1; d < 8; d <<= 1) {
      const float ov = __shfl_xor(bv, d, 64);
      const int oi = __shfl_xor(bi, d, 64);
      if (ov > bv || (ov == bv && oi < bi)) { bv = ov; bi = oi; }
    }
    if (s == 0) {
      inds1[p0 + p] = (unsigned char)bi;
      mask_out[p0 + p] = m > 0.f ? m : 0.01f * m;
      atomicAdd(&lh[bi], 1);
    }
  }
  __syncthreads();
  if (t < 16 && lh[t] > 0) atomicAdd(&cnt1[t], lh[t]);
}

// parallel scan + descriptor emit
template<int NB>
__global__ __launch_bounds__(256) void scan_desc_k(const int* __restrict__ cnt,
    int* __restrict__ off, int* __restrict__ desc, int* __restrict__ ndesc) {
  const int t = threadIdx.x;
  const int lane = t & 63, wvi = t >> 6;
  __shared__ int wsumC[4], wsumD[4];
  const int c = (t < NB) ? cnt[t] : 0;
  const int nb = (c + TPB - 1) / TPB;
  int ic = c, id = nb;
  for (int d = 1; d < 64; d <<= 1) {
    const int uc = __shfl_up(ic, d, 64);
    const int ud = __shfl_up(id, d, 64);
    if (lane >= d) { ic += uc; id += ud; }
  }
  if (lane == 63) { wsumC[wvi] = ic; wsumD[wvi] = id; }
  __syncthreads();
  int bc = 0, bd = 0;
#pragma unroll
  for (int w2 = 0; w2 < 4; ++w2) {
    if (w2 < wvi) { bc += wsumC[w2]; bd += wsumD[w2]; }
  }
  ic += bc; id += bd;
  if (t < NB) {
    off[t] = ic - c;
    const int db = id - nb;
    for (int j = 0; j < nb; ++j) desc[db + j] = (t << 12) | j;
  }
  if (t == NB - 1) *ndesc = id;
}

// two-level scatter
template<typename T>
__global__ __launch_bounds__(256) void scatter_k(const T* __restrict__ bins,
    const int* __restrict__ off, int* __restrict__ cursor,
    int* __restrict__ ord, int nbins) {
  __shared__ int lhist[256], lbase[256], lcur[256];
  const int t = threadIdx.x;
  const int n = blockIdx.x * 256 + t;
  if (t < nbins) { lhist[t] = 0; lcur[t] = 0; }
  __syncthreads();
  const int b = (int)bins[n];
  atomicAdd(&lhist[b], 1);
  __syncthreads();
  if (t < nbins && lhist[t] > 0) lbase[t] = atomicAdd(&cursor[t], lhist[t]);
  __syncthreads();
  const int r = atomicAdd(&lcur[b], 1);
  ord[off[b] + lbase[b] + r] = n;
}

// ---------------------------------------------------------------------------
// chain1 v5 (unchanged): LDS-staged expert weights + x rows; pure-LDS k-loop.
// ---------------------------------------------------------------------------
__global__ __launch_bounds__(256) void chain1_k(const float* __restrict__ xt,
    const int* __restrict__ ord1, const int* __restrict__ off1,
    const int* __restrict__ cnt1, const int* __restrict__ desc1,
    const int* __restrict__ nd1,
    const float* __restrict__ wc21, const float* __restrict__ bc21,
    const float* __restrict__ wc22, const float* __restrict__ bc22,
    const float* __restrict__ wc23, const float* __restrict__ bc23,
    int* __restrict__ e12a, int* __restrict__ cnt2) {
  if ((int)blockIdx.x >= *nd1) return;
  __shared__ float w1s[4096];
  __shared__ float w2s[1024];
  __shared__ float w3s[512];
  __shared__ float bs[80];
  __shared__ float xs_[64][132];
  __shared__ int lh[16];
  const int t = threadIdx.x;
  if (t < 16) lh[t] = 0;
  const int tg = t >> 2, sub = t & 3;
  const int l0 = (t & 63) & ~3;
  const int de = desc1[blockIdx.x];
  const int e = de >> 12, chunk = de & 0xFFF;
  const int cnt = cnt1[e];
  const int pos = chunk * TPB + tg;
  const bool valid = pos < cnt;
  const int n = valid ? ord1[off1[e] + pos] : 0;

  {
    const float4* __restrict__ Wg1 = (const float4*)(wc21 + e * 4096);
#pragma unroll
    for (int j = 0; j < 4; ++j)
      *(float4*)&w1s[t * 4 + j * 1024] = Wg1[t + j * 256];
    const float4* __restrict__ Wg2 = (const float4*)(wc22 + e * 1024);
    *(float4*)&w2s[t * 4] = Wg2[t];
    if (t < 128) {
      const float4* __restrict__ Wg3 = (const float4*)(wc23 + e * 512);
      *(float4*)&w3s[t * 4] = Wg3[t];
    }
    if (t < 32) bs[t] = bc21[e * 32 + t];
    else if (t < 64) bs[t] = bc22[e * 32 + (t - 32)];
    else if (t < 80) bs[t] = bc23[e * 16 + (t - 64)];
  }
  {
    const float4* __restrict__ src = (const float4*)(xt + n * 128 + sub * 32);
    float4 tmp[8];
#pragma unroll
    for (int j = 0; j < 8; ++j) tmp[j] = src[j];
#pragma unroll
    for (int j = 0; j < 8; ++j)
      *(float4*)(&xs_[tg][sub * 32 + 4 * j]) = tmp[j];
  }
  __syncthreads();

  const int wb1 = sub * 8;
  float a[8];
#pragma unroll
  for (int o = 0; o < 8; ++o) a[o] = bs[wb1 + o];
#pragma unroll
  for (int k = 0; k < 128; k += 4) {
    float x4[4];
    *(float4*)x4 = *(const float4*)(&xs_[tg][k]);
#pragma unroll
    for (int kk = 0; kk < 4; ++kk) {
      float w8[8];
      *(float4*)&w8[0] = *(const float4*)&w1s[(k + kk) * 32 + wb1];
      *(float4*)&w8[4] = *(const float4*)&w1s[(k + kk) * 32 + wb1 + 4];
#pragma unroll
      for (int o = 0; o < 8; ++o) a[o] = fmaf(x4[kk], w8[o], a[o]);
    }
  }
#pragma unroll
  for (int o = 0; o < 8; ++o) a[o] = a[o] > 0.f ? a[o] : 0.01f * a[o];

  float b[8];
#pragma unroll
  for (int o = 0; o < 8; ++o) b[o] = bs[32 + wb1 + o];
#pragma unroll
  for (int i = 0; i < 32; ++i) {
    const float hv = __shfl(a[i & 7], l0 + (i >> 3), 64);
    float w8[8];
    *(float4*)&w8[0] = *(const float4*)&w2s[i * 32 + wb1];
    *(float4*)&w8[4] = *(const float4*)&w2s[i * 32 + wb1 + 4];
#pragma unroll
    for (int o = 0; o < 8; ++o) b[o] = fmaf(hv, w8[o], b[o]);
  }
#pragma unroll
  for (int o = 0; o < 8; ++o) b[o] = b[o] > 0.f ? b[o] : 0.01f * b[o];

  float s[4];
#pragma unroll
  for (int j = 0; j < 4; ++j) s[j] = bs[64 + sub * 4 + j];
#pragma unroll
  for (int i = 0; i < 32; ++i) {
    const float hv = __shfl(b[i & 7], l0 + (i >> 3), 64);
    float w4[4];
    *(float4*)w4 = *(const float4*)&w3s[i * 16 + sub * 4];
#pragma unroll
    for (int j = 0; j < 4; ++j) s[j] = fmaf(hv, w4[j], s[j]);
  }

  float bv = s[0];
  int bi = sub * 4;
#pragma unroll
  for (int j = 1; j < 4; ++j) {
    if (s[j] > bv) { bv = s[j]; bi = sub * 4 + j; }
  }
#pragma unroll
  for (int d = 1; d < 4; d <<= 1) {
    const float ov = __shfl_xor(bv, d, 64);
    const int oi = __shfl_xor(bi, d, 64);
    if (ov > bv || (ov == bv && oi < bi)) { bv = ov; bi = oi; }
  }
  const int e12 = e * 16 + bi;
  if (valid && sub == 0) {
    e12a[n] = e12;
    atomicAdd(&lh[bi], 1);
  }
  __syncthreads();
  if (t < 16 && lh[t] > 0)
    atomicAdd(&cnt2[e * 16 + t], lh[t]);
}

// ---------------------------------------------------------------------------
// chain2 v5 (unchanged): LDS-weight-staged. Writes out[n].
// ---------------------------------------------------------------------------
__global__ __launch_bounds__(256) void chain2_k(const float* __restrict__ xt,
    const int* __restrict__ ord2, const int* __restrict__ off2,
    const int* __restrict__ cnt2, const int* __restrict__ desc2,
    const int* __restrict__ nd2,
    const float* __restrict__ wr11, const float* __restrict__ br11,
    const float* __restrict__ wr12, const float* __restrict__ br12,
    const float* __restrict__ wr13, const float* __restrict__ br13,
    float* __restrict__ out) {
  if ((int)blockIdx.x >= *nd2) return;
  __shared__ float w1s[4096];
  __shared__ float w2s[512];
  __shared__ float w3s[16];
  __shared__ float bs[49];
  __shared__ float xs_[64][132];
  const int t = threadIdx.x;
  const int tg = t >> 2, sub = t & 3;
  const int l0 = (t & 63) & ~3;
  const int de = desc2[blockIdx.x];
  const int e12 = de >> 12, chunk = de & 0xFFF;
  const int cnt = cnt2[e12];
  const int pos = chunk * TPB + tg;
  const bool valid = pos < cnt;
  const int n = valid ? ord2[off2[e12] + pos] : 0;

  {
    const float4* __restrict__ Wg1 = (const float4*)(wr11 + e12 * 4096);
#pragma unroll
    for (int j = 0; j < 4; ++j)
      *(float4*)&w1s[t * 4 + j * 1024] = Wg1[t + j * 256];
    if (t < 128) {
      const float4* __restrict__ Wg2 = (const float4*)(wr12 + e12 * 512);
      *(float4*)&w2s[t * 4] = Wg2[t];
    }
    if (t < 16) w3s[t] = wr13[e12 * 16 + t];
    if (t < 32) bs[t] = br11[e12 * 32 + t];
    else if (t < 48) bs[t] = br12[e12 * 16 + (t - 32)];
    else if (t == 48) bs[48] = br13[e12];
  }
  {
    const float4* __restrict__ src = (const float4*)(xt + n * 128 + sub * 32);
    float4 tmp[8];
#pragma unroll
    for (int j = 0; j < 8; ++j) tmp[j] = src[j];
#pragma unroll
    for (int j = 0; j < 8; ++j)
      *(float4*)(&xs_[tg][sub * 32 + 4 * j]) = tmp[j];
  }
  __syncthreads();

  const int wb1 = sub * 8;
  float a[8];
#pragma unroll
  for (int o = 0; o < 8; ++o) a[o] = bs[wb1 + o];
#pragma unroll
  for (int k = 0; k < 128; k += 4) {
    float x4[4];
    *(float4*)x4 = *(const float4*)(&xs_[tg][k]);
#pragma unroll
    for (int kk = 0; kk < 4; ++kk) {
      float w8[8];
      *(float4*)&w8[0] = *(const float4*)&w1s[(k + kk) * 32 + wb1];
      *(float4*)&w8[4] = *(const float4*)&w1s[(k + kk) * 32 + wb1 + 4];
#pragma unroll
      for (int o = 0; o < 8; ++o) a[o] = fmaf(x4[kk], w8[o], a[o]);
    }
  }
#pragma unroll
  for (int o = 0; o < 8; ++o) a[o] = a[o] > 0.f ? a[o] : 0.01f * a[o];

  float s[4];
#pragma unroll
  for (int j = 0; j < 4; ++j) s[j] = bs[32 + sub * 4 + j];
#pragma unroll
  for (int i = 0; i < 32; ++i) {
    const float hv = __shfl(a[i & 7], l0 + (i >> 3), 64);
    float w4[4];
    *(float4*)w4 = *(const float4*)&w2s[i * 16 + sub * 4];
#pragma unroll
    for (int j = 0; j < 4; ++j) s[j] = fmaf(hv, w4[j], s[j]);
  }
#pragma unroll
  for (int j = 0; j < 4; ++j) s[j] = s[j] > 0.f ? s[j] : 0.01f * s[j];

  float r = bs[48];
#pragma unroll
  for (int i = 0; i < 16; ++i) {
    const float hv = __shfl(s[i & 3], l0 + (i >> 2), 64);
    r = fmaf(hv, w3s[i], r);
  }

  if (valid && sub == 0) out[n] = ((float)e12 + r) * (1.0f / 256.0f);
}

// ---------------------------------------------------------------------------
extern "C" void kernel_launch(void* const* d_in, const int* in_sizes, int n_in,
                              void* d_out, int out_size, void* d_ws,
                              size_t ws_size, hipStream_t stream) {
  const float* x_in  = (const float*)d_in[0];
  const float* w_c11 = (const float*)d_in[1];
  const float* b_c11 = (const float*)d_in[2];
  const float* w_c12 = (const float*)d_in[3];
  const float* b_c12 = (const float*)d_in[4];
  const float* w_c13 = (const float*)d_in[5];
  const float* b_c13 = (const float*)d_in[6];
  const float* w_c21 = (const float*)d_in[7];
  const float* b_c21 = (const float*)d_in[8];
  const float* w_c22 = (const float*)d_in[9];
  const float* b_c22 = (const float*)d_in[10];
  const float* w_c23 = (const float*)d_in[11];
  const float* b_c23 = (const float*)d_in[12];
  const float* w_r11 = (const float*)d_in[13];
  const float* b_r11 = (const float*)d_in[14];
  const float* w_r12 = (const float*)d_in[15];
  const float* b_r12 = (const float*)d_in[16];
  const float* w_r13 = (const float*)d_in[17];
  const float* b_r13 = (const float*)d_in[18];

  float* out = (float*)d_out;   // [0..N): x_real (token order), [N..2N): mask

  float* R0 = (float*)d_ws;
  float* R1 = R0 + 128 * NPIX;
  float* R2 = R1 + 128 * NPIX;

  float* xt = R0;
  unsigned char* inds1 = (unsigned char*)R2;   // N bytes
  float* wT1 = R2 + 12288;
  float* wT2 = wT1 + 16384;
  int* S = (int*)R2 + 45056;

  int* cnt1  = S;            // 16
  int* cur1  = S + 16;       // 16
  int* off1  = S + 32;       // 16
  int* nd1   = S + 48;       // 1 (+pad)
  int* desc1 = S + 64;       // 1024
  int* cnt2  = S + 1088;     // 256
  int* cur2  = S + 1344;     // 256
  int* off2  = S + 1600;     // 256
  int* nd2   = S + 1856;     // 1 (+pad)
  int* desc2 = S + 1872;     // 1024

  int* ib   = (int*)R1;
  int* ord1 = ib;            // N
  int* ord2 = ib + NPIX;     // N
  int* e12a = ib + 2 * NPIX; // N

  wtrans2_k<<<32, 256, 0, stream>>>(w_c11, wT1, w_c12, wT2, S);
  convfused_k<<<NPIX / 64, 512, 0, stream>>>(x_in, wT1, b_c11, wT2, b_c12,
      w_c13, b_c13, inds1, out + NPIX, cnt1, xt);
  scan_desc_k<16><<<1, 256, 0, stream>>>(cnt1, off1, desc1, nd1);
  scatter_k<unsigned char><<<NPIX / 256, 256, 0, stream>>>(inds1, off1, cur1,
                                                           ord1, 16);
  chain1_k<<<NPIX / TPB + 16, 256, 0, stream>>>(xt, ord1, off1, cnt1, desc1,
      nd1, w_c21, b_c21, w_c22, b_c22, w_c23, b_c23, e12a, cnt2);
  scan_desc_k<256><<<1, 256, 0, stream>>>(cnt2, off2, desc2, nd2);
  scatter_k<int><<<NPIX / 256, 256, 0, stream>>>(e12a, off2, cur2, ord2, 256);
  chain2_k<<<NPIX / TPB + 256, 256, 0, stream>>>(xt, ord2, off2, cnt2, desc2,
      nd2, w_r11, b_r11, w_r12, b_r12, w_r13, b_r13, out);
}